// Round 8
// baseline (982.875 us; speedup 1.0000x reference)
//
#include <hip/hip_runtime.h>
#include <hip/hip_bf16.h>

#define NN 100000
#define EE 1600000
#define GG 64
#define HH 128
#define LL 3
#define BN_EPS 1e-5f
#define NBUCK 196          // ceil(NN/512)
#define BCAP 12288         // bucket capacity (mean 8163, +45 sigma safe)
#define PART_CHUNK 8192
#define NREP 16            // stats replicas (atomic contention /16)

typedef __attribute__((ext_vector_type(8))) short bf16x8;
typedef __attribute__((ext_vector_type(4))) float f32x4;
typedef unsigned int uint32;

__device__ __forceinline__ float bflo(uint32 u) { return __uint_as_float(u << 16); }
__device__ __forceinline__ float bfhi(uint32 u) { return __uint_as_float(u & 0xffff0000u); }
__device__ __forceinline__ unsigned short f2bf(float f) {
    uint32 x = __float_as_uint(f);
    uint32 r = (x + 0x7fffu + ((x >> 16) & 1u)) >> 16;
    return (unsigned short)r;
}
__device__ __forceinline__ float bf2f(unsigned short u) { return __uint_as_float(((uint32)u) << 16); }
// dequant-accumulate 4 unsigned uint8 channels with per-row scale
__device__ __forceinline__ void accq(float4& a, uint32 u, float sc) {
    a.x += sc * (float)(u & 0xffu);
    a.y += sc * (float)((u >> 8) & 0xffu);
    a.z += sc * (float)((u >> 16) & 0xffu);
    a.w += sc * (float)(u >> 24);
}
// dequant-accumulate 4 signed int8 channels with per-row scale
__device__ __forceinline__ void accqs(float4& a, uint32 u, float sc) {
    a.x += sc * (float)((int)(u << 24) >> 24);
    a.y += sc * (float)((int)(u << 16) >> 24);
    a.z += sc * (float)((int)(u << 8) >> 24);
    a.w += sc * (float)((int)u >> 24);
}

// ---------------- bucketed edge partition ----------------
__global__ __launch_bounds__(256) void partition_kernel(
    const int* __restrict__ src, const int* __restrict__ dst,
    int* __restrict__ bcnt, uint32* __restrict__ part) {
    __shared__ int cnt[NBUCK];
    __shared__ int loff[NBUCK + 1];
    __shared__ int gpos[NBUCK];
    __shared__ int lcur[NBUCK];
    __shared__ uint32 buf[PART_CHUNK];
    int tid = threadIdx.x;
    int base = blockIdx.x * PART_CHUNK;
    int n = min(PART_CHUNK, EE - base);
    for (int i = tid; i < NBUCK; i += 256) { cnt[i] = 0; lcur[i] = 0; }
    __syncthreads();
    for (int i = tid; i < n; i += 256) atomicAdd(&cnt[dst[base + i] >> 9], 1);
    __syncthreads();
    if (tid == 0) {
        int acc = 0;
        for (int b = 0; b < NBUCK; ++b) { loff[b] = acc; acc += cnt[b]; }
        loff[NBUCK] = acc;
    }
    __syncthreads();
    if (tid < NBUCK && cnt[tid] > 0) gpos[tid] = atomicAdd(&bcnt[tid], cnt[tid]);
    __syncthreads();
    for (int i = tid; i < n; i += 256) {
        int d = dst[base + i];
        int s = src[base + i];
        int b = d >> 9;
        int slot = atomicAdd(&lcur[b], 1);
        buf[loff[b] + slot] = (uint32)s | ((uint32)(d & 511) << 17);
    }
    __syncthreads();
    for (int i = tid; i < n; i += 256) {
        int lo = 0, hi = NBUCK;
        while (hi - lo > 1) { int mid = (lo + hi) >> 1; if (loff[mid] <= i) lo = mid; else hi = mid; }
        part[(size_t)lo * BCAP + gpos[lo] + (i - loff[lo])] = buf[i];
    }
}

// ---------------- build per-bucket CSR + col (in LDS) ----------------
__global__ __launch_bounds__(256) void build_col_kernel(
    const uint32* __restrict__ part, const int* __restrict__ bcnt,
    int* __restrict__ col, int2* __restrict__ rowpair) {
    __shared__ int ldeg[512];
    __shared__ int loffn[512];
    __shared__ int lcur[512];
    __shared__ int pscan[256];
    __shared__ int cl[BCAP];
    int b = blockIdx.x;
    int tid = threadIdx.x;
    int node0 = b << 9;
    int nn = min(node0 + 512, NN) - node0;
    int cnt = bcnt[b];
    int base = b * BCAP;
    const uint32* pp = part + (size_t)base;
    for (int i = tid; i < 512; i += 256) { ldeg[i] = 0; lcur[i] = 0; }
    __syncthreads();
    for (int i = tid; i < cnt; i += 256) atomicAdd(&ldeg[pp[i] >> 17], 1);
    __syncthreads();
    int t2 = tid * 2;
    int a0 = ldeg[t2], a1 = ldeg[t2 + 1];
    int ps = a0 + a1;
    pscan[tid] = ps;
    __syncthreads();
    for (int off = 1; off < 256; off <<= 1) {
        int v = (tid >= off) ? pscan[tid - off] : 0;
        __syncthreads();
        pscan[tid] += v;
        __syncthreads();
    }
    int eo = pscan[tid] - ps;
    loffn[t2] = eo;
    loffn[t2 + 1] = eo + a0;
    if (t2 < nn)     rowpair[node0 + t2]     = make_int2(base + eo, base + eo + a0);
    if (t2 + 1 < nn) rowpair[node0 + t2 + 1] = make_int2(base + eo + a0, base + eo + a0 + a1);
    __syncthreads();
    for (int i = tid; i < cnt; i += 256) {
        uint32 v = pp[i];
        int dl = (int)(v >> 17);
        int pos = atomicAdd(&lcur[dl], 1);
        cl[loffn[dl] + pos] = (int)(v & 0x1FFFFu);
    }
    __syncthreads();
    for (int i = tid; i < cnt; i += 256) col[base + i] = cl[i];
}

// ---------------- graph counts ----------------
__global__ void counts_kernel(const int* __restrict__ batch, float* __restrict__ cnt, int n) {
    __shared__ int h[GG];
    int tid = threadIdx.x;
    if (tid < GG) h[tid] = 0;
    __syncthreads();
    int i = blockIdx.x * 256 + tid;
    if (i < n) atomicAdd(&h[batch[i]], 1);
    __syncthreads();
    if (tid < GG && h[tid]) atomicAdd(&cnt[tid], (float)h[tid]);
}

// ---------------- x -> int8 row-quantized ----------------
__global__ void x_to_i8_kernel(const float* __restrict__ x, unsigned short* __restrict__ x8,
                               float* __restrict__ sc0) {
    int row = (blockIdx.x * 256 + threadIdx.x) >> 6;
    int lane = threadIdx.x & 63;
    if (row >= NN) return;
    float2 v = ((const float2*)x)[(size_t)row * 64 + lane];
    float m = fmaxf(fabsf(v.x), fabsf(v.y));
#pragma unroll
    for (int off = 1; off < 64; off <<= 1) m = fmaxf(m, __shfl_xor(m, off));
    float scale = m * (1.f / 127.f);
    float inv = (m > 0.f) ? 127.f / m : 0.f;
    int b0 = __float2int_rn(v.x * inv);
    int b1 = __float2int_rn(v.y * inv);
    unsigned short pk = (unsigned short)((b0 & 0xff) | ((b1 & 0xff) << 8));
    x8[(size_t)row * 64 + lane] = pk;
    if (lane == 0) sc0[row] = scale;
}

#define MAT_STRIDE 16384   // ushort elements per frag-ordered matrix

// frag-order weights: [br(2)][l(3)][mat(2)][nt(8)][ks(4)][lane(64)][j(8)]
__global__ void convert_w_kernel(const float* __restrict__ W1a, const float* __restrict__ W2a,
                                 const float* __restrict__ W1b, const float* __restrict__ W2b,
                                 unsigned short* __restrict__ out) {
    int t = blockIdx.x * 256 + threadIdx.x;
    if (t >= 24576) return;
    int lane = t & 63;
    int r = t >> 6;
    int ks = r & 3; r >>= 2;
    int nt = r & 7; r >>= 3;
    int mat = r & 1; r >>= 1;
    int l = r % 3, br = r / 3;
    const float* W = br ? (mat ? W2b : W1b) : (mat ? W2a : W1a);
    const float* Wl = W + (size_t)l * 128 * 128;
    int n0 = nt * 16 + (lane & 15);
    int k0 = ks * 32 + (lane >> 4) * 8;
    unsigned short tmp[8];
#pragma unroll
    for (int j = 0; j < 8; ++j) tmp[j] = f2bf(Wl[(size_t)(k0 + j) * 128 + n0]);
    size_t seq = (size_t)(br * 3 + l) * 2 + mat;
    size_t off = (((seq * 8 + nt) * 4 + ks) * 64 + (size_t)lane) * 8;
    *(uint4*)(out + off) = *(const uint4*)tmp;
}

// ---------------- BN coefs from replicated stats ----------------
// coef layout per layer: [br][A(128) | B(128)]  (256 floats per branch)
__global__ void bn_coefs_kernel(const float* __restrict__ statsRep,
                                const float* __restrict__ ga, const float* __restrict__ bta,
                                const float* __restrict__ gb, const float* __restrict__ btb,
                                int l, float* __restrict__ coef) {
    int t = threadIdx.x;        // 256: br*128+cc
    int br = t >> 7, cc = t & 127;
    const float* base = statsRep + (size_t)((l * 2 + br) * NREP) * 256;
    float s = 0.f, sq = 0.f;
#pragma unroll
    for (int rep = 0; rep < NREP; ++rep) {
        s += base[rep * 256 + cc];
        sq += base[rep * 256 + 128 + cc];
    }
    float mu = s * (1.f / NN);
    float var = sq * (1.f / NN) - mu * mu;
    float gm = (br ? gb : ga)[l * 128 + cc];
    float A = gm * rsqrtf(var + BN_EPS);
    float B = (br ? btb : bta)[l * 128 + cc] - mu * A;
    coef[br * 256 + cc] = A;
    coef[br * 256 + 128 + cc] = B;
}

// ---------------- layer-0 gather on int8 x ----------------
__global__ void gather0_kernel(const uint32* __restrict__ x8, const float* __restrict__ sc0,
                               const int2* __restrict__ rowpair, const int* __restrict__ col,
                               uint2* __restrict__ out) {
    int gw = (blockIdx.x * blockDim.x + threadIdx.x) >> 6;
    int lane = threadIdx.x & 63;
    if (gw >= NN) return;
    int slot = lane >> 5;
    int c = lane & 31;
    float4 acc = {0.f, 0.f, 0.f, 0.f};
    if (slot == 0) accqs(acc, x8[(size_t)gw * 32 + c], sc0[gw]);
    int2 be = rowpair[gw];
    int beg = be.x, end = be.y;
    int e = beg;
    for (; e + 4 <= end; e += 4) {
        int j0 = col[e + slot], j1 = col[e + 2 + slot];
        uint32 u0 = x8[(size_t)j0 * 32 + c]; float s0 = sc0[j0];
        uint32 u1 = x8[(size_t)j1 * 32 + c]; float s1 = sc0[j1];
        accqs(acc, u0, s0);
        accqs(acc, u1, s1);
    }
    for (; e + 2 <= end; e += 2) {
        int j = col[e + slot];
        accqs(acc, x8[(size_t)j * 32 + c], sc0[j]);
    }
    if (e < end && slot == 0) {
        int j = col[e];
        accqs(acc, x8[(size_t)j * 32 + c], sc0[j]);
    }
    acc.x += __shfl_xor(acc.x, 32);
    acc.y += __shfl_xor(acc.y, 32);
    acc.z += __shfl_xor(acc.z, 32);
    acc.w += __shfl_xor(acc.w, 32);
    if (slot == 0) {
        uint2 o;
        o.x = (uint32)f2bf(acc.x) | ((uint32)f2bf(acc.y) << 16);
        o.y = (uint32)f2bf(acc.z) | ((uint32)f2bf(acc.w) << 16);
        out[(size_t)gw * 32 + c] = o;
    }
}

// ================= shared MLP device body (GEMM1+GEMM2+epilogue) =================
// hs[wv] holds the 16 input rows (bf16). Returns via epilogue writes.
__device__ __forceinline__ void mlp_body(
    unsigned short (*hs)[16][136], float* ssum, float* ssq,
    const unsigned short* Wf, const float* b1, const float* b2,
    int wv, int lane, int quad, int l16, int row0, int n, int br, int quant,
    unsigned short* Y, unsigned char* Y8, float* scales) {
    const bf16x8* w2g = (const bf16x8*)(Wf + MAT_STRIDE);
    unsigned char* hs8 = (unsigned char*)&hs[wv][0][0];

    bf16x8 aF[4];
#pragma unroll
    for (int ks = 0; ks < 4; ++ks)
        aF[ks] = *(const bf16x8*)(&hs[wv][l16][ks * 32 + quad * 8]);

    // GEMM1: W1 from LDS (staged) -- passed via Wf? No: w1s global LDS declared by caller.
    // (W1 LDS pointer passed through hs trick not possible; caller stages w1s and we read it.)
    extern __shared__ unsigned short lds_all[];   // w1s at offset 0
    const unsigned short* w1s = lds_all;

    f32x4 acc1[8];
#pragma unroll
    for (int nt = 0; nt < 8; ++nt) {
        f32x4 c = {0.f, 0.f, 0.f, 0.f};
#pragma unroll
        for (int ks = 0; ks < 4; ++ks) {
            bf16x8 bfrag = *(const bf16x8*)(&w1s[((nt * 4 + ks) * 64 + lane) * 8]);
            c = __builtin_amdgcn_mfma_f32_16x16x32_bf16(aF[ks], bfrag, c, 0, 0, 0);
        }
        acc1[nt] = c;
    }

#pragma unroll
    for (int nt = 0; nt < 8; ++nt) {
        int c0 = nt * 16 + l16;
        float bb = b1[c0];
#pragma unroll
        for (int r = 0; r < 4; ++r) {
            float v = fmaxf(acc1[nt][r] + bb, 0.f);
            hs[wv][quad * 4 + r][c0] = f2bf(v);
        }
    }

    bf16x8 aH[4];
#pragma unroll
    for (int ks = 0; ks < 4; ++ks)
        aH[ks] = *(const bf16x8*)(&hs[wv][l16][ks * 32 + quad * 8]);

    f32x4 acc2_[8];
#pragma unroll
    for (int nt = 0; nt < 8; ++nt) {
        bf16x8 bf0 = w2g[(nt * 4 + 0) * 64 + lane];
        bf16x8 bf1 = w2g[(nt * 4 + 1) * 64 + lane];
        bf16x8 bf2 = w2g[(nt * 4 + 2) * 64 + lane];
        bf16x8 bf3 = w2g[(nt * 4 + 3) * 64 + lane];
        f32x4 c = {0.f, 0.f, 0.f, 0.f};
        c = __builtin_amdgcn_mfma_f32_16x16x32_bf16(aH[0], bf0, c, 0, 0, 0);
        c = __builtin_amdgcn_mfma_f32_16x16x32_bf16(aH[1], bf1, c, 0, 0, 0);
        c = __builtin_amdgcn_mfma_f32_16x16x32_bf16(aH[2], bf2, c, 0, 0, 0);
        c = __builtin_amdgcn_mfma_f32_16x16x32_bf16(aH[3], bf3, c, 0, 0, 0);
        acc2_[nt] = c;
    }

#pragma unroll
    for (int nt = 0; nt < 8; ++nt) {
        int c0 = nt * 16 + l16;
        float bb = b2[c0];
        float s = 0.f, sq = 0.f;
#pragma unroll
        for (int r = 0; r < 4; ++r) {
            float v = fmaxf(acc2_[nt][r] + bb, 0.f);
            if (row0 + quad * 4 + r >= n) v = 0.f;
            acc2_[nt][r] = v;
            s += v; sq += v * v;
        }
        s += __shfl_xor(s, 16); s += __shfl_xor(s, 32);
        sq += __shfl_xor(sq, 16); sq += __shfl_xor(sq, 32);
        if (quad == 0) { atomicAdd(&ssum[c0], s); atomicAdd(&ssq[c0], sq); }
    }

    if (!quant) {
#pragma unroll
        for (int nt = 0; nt < 8; ++nt) {
            int c0 = nt * 16 + l16;
#pragma unroll
            for (int r = 0; r < 4; ++r) hs[wv][quad * 4 + r][c0] = f2bf(acc2_[nt][r]);
        }
        int grow = row0 + l16;
        if (grow < n) {
#pragma unroll
            for (int j = 0; j < 4; ++j) {
                uint4 v = *(const uint4*)(&hs[wv][l16][quad * 32 + j * 8]);
                *(uint4*)(Y + (size_t)grow * 256 + br * 128 + quad * 32 + j * 8) = v;
            }
        }
    } else {
#pragma unroll
        for (int r = 0; r < 4; ++r) {
            float m = acc2_[0][r];
#pragma unroll
            for (int nt = 1; nt < 8; ++nt) m = fmaxf(m, acc2_[nt][r]);
            m = fmaxf(m, __shfl_xor(m, 1));
            m = fmaxf(m, __shfl_xor(m, 2));
            m = fmaxf(m, __shfl_xor(m, 4));
            m = fmaxf(m, __shfl_xor(m, 8));
            float sc = m * (1.f / 255.f);
            float inv = (m > 0.f) ? 255.f / m : 0.f;
            int grow = row0 + quad * 4 + r;
            if (l16 == r && grow < n) scales[grow * 2 + br] = sc;
#pragma unroll
            for (int nt = 0; nt < 8; ++nt) {
                uint32 u = (uint32)__float2int_rn(acc2_[nt][r] * inv);
                hs8[(quad * 4 + r) * 144 + nt * 16 + l16] = (unsigned char)u;
            }
        }
        int grow = row0 + l16;
        if (grow < n) {
            *(uint4*)(Y8 + (size_t)grow * 256 + br * 128 + quad * 32) =
                *(const uint4*)(hs8 + l16 * 144 + quad * 32);
            *(uint4*)(Y8 + (size_t)grow * 256 + br * 128 + quad * 32 + 16) =
                *(const uint4*)(hs8 + l16 * 144 + quad * 32 + 16);
        }
    }
}

// ---------------- layer-0 MLP: bf16 g0 input (both branches), W1 in LDS ----------------
// dynamic LDS: w1s[16384 ushorts] | hs[4][16][136] | ssum[128] | ssq[128]
#define LDS_W1 16384
#define LDS_HS (4 * 16 * 136)
__global__ __launch_bounds__(256, 3) void mlp0_kernel(
    const unsigned short* __restrict__ X, const unsigned short* __restrict__ wf_all,
    const float* __restrict__ b1a, const float* __restrict__ b1b,
    const float* __restrict__ b2a, const float* __restrict__ b2b,
    unsigned char* __restrict__ Y8, float* __restrict__ scales,
    float* __restrict__ statsRep, int n) {
    extern __shared__ unsigned short lds_all[];
    unsigned short* w1s = lds_all;
    unsigned short (*hs)[16][136] = (unsigned short (*)[16][136])(lds_all + LDS_W1);
    float* ssum = (float*)(lds_all + LDS_W1 + LDS_HS);
    float* ssq = ssum + 128;

    int br = blockIdx.y;
    const unsigned short* Wf = wf_all + (size_t)(br * 3 + 0) * 2 * MAT_STRIDE;
    const float* b1 = (br ? b1b : b1a);
    const float* b2 = (br ? b2b : b2a);
    float* statsp = statsRep + (size_t)((0 * 2 + br) * NREP + (blockIdx.x & (NREP - 1))) * 256;

    int tid = threadIdx.x;
    int wv = tid >> 6, lane = tid & 63;
    int quad = lane >> 4, l16 = lane & 15;

    {
        const uint4* srcp = (const uint4*)Wf;
        uint4* dstp = (uint4*)w1s;
        for (int i = tid; i < 2048; i += 256) dstp[i] = srcp[i];
    }
    if (tid < 128) { ssum[tid] = 0.f; ssq[tid] = 0.f; }
    __syncthreads();

    int row0 = blockIdx.x * 64 + wv * 16;

    // load 16 rows of g0 into hs (bf16, stride 128)
    {
        int r = row0 + l16;
        if (r >= n) r = n - 1;
        const unsigned short* xrow = X + (size_t)r * 128;
#pragma unroll
        for (int ks = 0; ks < 4; ++ks) {
            uint4 v = *(const uint4*)(xrow + ks * 32 + quad * 8);
            *(uint4*)(&hs[wv][l16][ks * 32 + quad * 8]) = v;
        }
    }

    mlp_body(hs, ssum, ssq, Wf, b1, b2, wv, lane, quad, l16, row0, n, br, 1,
             nullptr, Y8, scales);

    __syncthreads();
    if (tid < 128) {
        atomicAdd(&statsp[tid], ssum[tid]);
        atomicAdd(&statsp[128 + tid], ssq[tid]);
    }
}

// ---------------- fused gather + MLP (layers 1,2) ----------------
__global__ __launch_bounds__(256, 3) void fused_layer_kernel(
    const uint32* __restrict__ y8in, const float* __restrict__ scin,
    const int2* __restrict__ rowpair, const int* __restrict__ col,
    const float* __restrict__ coef,     // this layer's BN-prev coefs [br][A|B]
    const unsigned short* __restrict__ wf_all,
    const float* __restrict__ b1a, const float* __restrict__ b1b,
    const float* __restrict__ b2a, const float* __restrict__ b2b,
    int l, int quant,
    unsigned short* __restrict__ Y, unsigned char* __restrict__ Y8out,
    float* __restrict__ scout, float* __restrict__ statsRep, int n) {
    extern __shared__ unsigned short lds_all[];
    unsigned short* w1s = lds_all;
    unsigned short (*hs)[16][136] = (unsigned short (*)[16][136])(lds_all + LDS_W1);
    float* ssum = (float*)(lds_all + LDS_W1 + LDS_HS);
    float* ssq = ssum + 128;

    int br = blockIdx.y;
    const unsigned short* Wf = wf_all + (size_t)(br * 3 + l) * 2 * MAT_STRIDE;
    const float* b1 = (br ? b1b : b1a) + l * 128;
    const float* b2 = (br ? b2b : b2a) + l * 128;
    float* statsp = statsRep + (size_t)((l * 2 + br) * NREP + (blockIdx.x & (NREP - 1))) * 256;

    int tid = threadIdx.x;
    int wv = tid >> 6, lane = tid & 63;
    int quad = lane >> 4, l16 = lane & 15;
    int slot = lane >> 5, cdw = lane & 31;

    {
        const uint4* srcp = (const uint4*)Wf;
        uint4* dstp = (uint4*)w1s;
        for (int i = tid; i < 2048; i += 256) dstp[i] = srcp[i];
    }
    if (tid < 128) { ssum[tid] = 0.f; ssq[tid] = 0.f; }
    __syncthreads();

    int row0 = blockIdx.x * 64 + wv * 16;

    // affine coefs for this lane's 4 channels (hoisted; same for all rows)
    float4 A4 = ((const float4*)(coef + br * 256))[cdw];
    float4 B4 = ((const float4*)(coef + br * 256 + 128))[cdw];

    // gather 16 rows serially; full 64 lanes: 2 edge slots x 32 ch-dwords
    for (int rr = 0; rr < 16; ++rr) {
        int row = row0 + rr;
        if (row >= n) {
            if (slot == 0) { uint2 z; z.x = 0; z.y = 0; *(uint2*)(&hs[wv][rr][cdw * 4]) = z; }
            continue;
        }
        float4 accA = {0.f, 0.f, 0.f, 0.f};
        float4 accB = {0.f, 0.f, 0.f, 0.f};
        if (slot == 0)
            accq(accA, y8in[(size_t)row * 64 + br * 32 + cdw], scin[row * 2 + br]);
        int2 be = rowpair[row];
        int e = be.x, end = be.y;
        float degp1 = (float)(end - e + 1);
        for (; e + 8 <= end; e += 8) {
            int j0 = col[e + slot], j1 = col[e + 2 + slot];
            int j2 = col[e + 4 + slot], j3 = col[e + 6 + slot];
            uint32 u0 = y8in[(size_t)j0 * 64 + br * 32 + cdw]; float s0 = scin[j0 * 2 + br];
            uint32 u1 = y8in[(size_t)j1 * 64 + br * 32 + cdw]; float s1 = scin[j1 * 2 + br];
            uint32 u2 = y8in[(size_t)j2 * 64 + br * 32 + cdw]; float s2 = scin[j2 * 2 + br];
            uint32 u3 = y8in[(size_t)j3 * 64 + br * 32 + cdw]; float s3 = scin[j3 * 2 + br];
            accq(accA, u0, s0);
            accq(accB, u1, s1);
            accq(accA, u2, s2);
            accq(accB, u3, s3);
        }
        for (; e + 2 <= end; e += 2) {
            int j = col[e + slot];
            accq(accA, y8in[(size_t)j * 64 + br * 32 + cdw], scin[j * 2 + br]);
        }
        if (e < end && slot == 0) {
            int j = col[e];
            accq(accA, y8in[(size_t)j * 64 + br * 32 + cdw], scin[j * 2 + br]);
        }
        accA.x += accB.x; accA.y += accB.y; accA.z += accB.z; accA.w += accB.w;
        accA.x += __shfl_xor(accA.x, 32);
        accA.y += __shfl_xor(accA.y, 32);
        accA.z += __shfl_xor(accA.z, 32);
        accA.w += __shfl_xor(accA.w, 32);
        if (slot == 0) {
            float o0 = A4.x * accA.x + B4.x * degp1;
            float o1 = A4.y * accA.y + B4.y * degp1;
            float o2 = A4.z * accA.z + B4.z * degp1;
            float o3 = A4.w * accA.w + B4.w * degp1;
            uint2 o;
            o.x = (uint32)f2bf(o0) | ((uint32)f2bf(o1) << 16);
            o.y = (uint32)f2bf(o2) | ((uint32)f2bf(o3) << 16);
            *(uint2*)(&hs[wv][rr][cdw * 4]) = o;
        }
    }

    mlp_body(hs, ssum, ssq, Wf, b1, b2, wv, lane, quad, l16, row0, n, br, quant,
             Y, Y8out, scout);

    __syncthreads();
    if (tid < 128) {
        atomicAdd(&statsp[tid], ssum[tid]);
        atomicAdd(&statsp[128 + tid], ssq[tid]);
    }
}

// ---------------- dual pooling (coefs precomputed) ----------------
#define POOL_CHUNK 128
__global__ void pool_dual_kernel(const unsigned short* __restrict__ h,
                                 const float* __restrict__ coef2,
                                 const int* __restrict__ batch,
                                 float* __restrict__ poolA, float* __restrict__ poolB, int n) {
    int t = threadIdx.x;
    int br = t >> 7, cc = t & 127;
    float a = coef2[br * 256 + cc];
    float b = coef2[br * 256 + 128 + cc];
    float* pool = br ? poolB : poolA;

    int i0 = blockIdx.x * POOL_CHUNK;
    if (i0 >= n) return;
    int i1 = min(i0 + POOL_CHUNK, n);
    float acc = 0.f;
    int cur = batch[i0];
    for (int i = i0; i < i1; ++i) {
        int g = batch[i];
        if (g != cur) {
            atomicAdd(&pool[cur * 128 + cc], acc);
            acc = 0.f;
            cur = g;
        }
        acc += a * bf2f(h[(size_t)i * 256 + t]) + b;
    }
    atomicAdd(&pool[cur * 128 + cc], acc);
}

// ---------------- bilinear discriminator ----------------
__global__ void disc_kernel(const float* __restrict__ poolB, const float* __restrict__ cnt,
                            const float* __restrict__ W, const float* __restrict__ db,
                            float* __restrict__ out) {
    int g = blockIdx.x, e = threadIdx.x;
    __shared__ float rs[128], rh[128];
    float invc = 1.f / fmaxf(cnt[g], 1.f);
    int gs = (g == 32) ? 30 : (63 - g);
    float invcs = 1.f / fmaxf(cnt[gs], 1.f);
    const float* a = poolB + g * 128;
    float t = 0.f;
    for (int d = 0; d < 128; ++d) t += a[d] * W[d * 128 + e];
    t *= invc;
    rs[e] = t * poolB[g * 128 + e] * invc;
    rh[e] = t * poolB[gs * 128 + e] * invcs;
    __syncthreads();
    for (int s = 64; s > 0; s >>= 1) {
        if (e < s) { rs[e] += rs[e + s]; rh[e] += rh[e + s]; }
        __syncthreads();
    }
    if (e == 0) {
        out[GG * 10 + g] = rs[0] + db[0];
        out[GG * 10 + GG + g] = rh[0] + db[0];
    }
}

// ---------------- classification head ----------------
__global__ void head_kernel(const float* __restrict__ poolA, const float* __restrict__ poolB,
                            const float* __restrict__ cnt,
                            const float* __restrict__ w1, const float* __restrict__ b1,
                            const float* __restrict__ w2, const float* __restrict__ b2,
                            float* __restrict__ out) {
    int g = blockIdx.x, j = threadIdx.x;
    __shared__ float s1[128];
    __shared__ float s2[10];
    __shared__ float lse;
    float invc = 1.f / fmaxf(cnt[g], 1.f);
    const float* ma = poolA + g * 128;
    const float* px = poolB + g * 128;
    float acc = b1[j];
    for (int k = 0; k < 128; ++k) acc += ma[k] * invc * w1[k * 128 + j];
    for (int k = 0; k < 128; ++k) acc += px[k] * invc * w1[(128 + k) * 128 + j];
    s1[j] = fmaxf(acc, 0.f);
    __syncthreads();
    if (j < 10) {
        float a = b2[j];
        for (int k = 0; k < 128; ++k) a += s1[k] * w2[k * 10 + j];
        s2[j] = a;
    }
    __syncthreads();
    if (j == 0) {
        float m = s2[0];
        for (int o = 1; o < 10; ++o) m = fmaxf(m, s2[o]);
        float se = 0.f;
        for (int o = 0; o < 10; ++o) se += expf(s2[o] - m);
        lse = m + logf(se);
    }
    __syncthreads();
    if (j < 10) out[g * 10 + j] = s2[j] - lse;
}

extern "C" void kernel_launch(void* const* d_in, const int* in_sizes, int n_in,
                              void* d_out, int out_size, void* d_ws, size_t ws_size,
                              hipStream_t stream) {
    const float* x     = (const float*)d_in[0];
    const int*   ei    = (const int*)d_in[1];
    const int*   batch = (const int*)d_in[2];
    const float* W1a = (const float*)d_in[3];
    const float* b1a = (const float*)d_in[4];
    const float* W2a = (const float*)d_in[5];
    const float* b2a = (const float*)d_in[6];
    const float* ga  = (const float*)d_in[7];
    const float* bta = (const float*)d_in[8];
    const float* W1b = (const float*)d_in[9];
    const float* b1b = (const float*)d_in[10];
    const float* W2b = (const float*)d_in[11];
    const float* b2b = (const float*)d_in[12];
    const float* gb  = (const float*)d_in[13];
    const float* btb = (const float*)d_in[14];
    const float* lin1_w = (const float*)d_in[15];
    const float* lin1_b = (const float*)d_in[16];
    const float* lin2_w = (const float*)d_in[17];
    const float* lin2_b = (const float*)d_in[18];
    const float* disc_w = (const float*)d_in[19];
    const float* disc_b = (const float*)d_in[20];
    float* out = (float*)d_out;

    const int* src = ei;
    const int* dst = ei + EE;

    size_t o = 0;
    auto take = [&](size_t b) { size_t p = o; o = (o + b + 255) & ~(size_t)255; return p; };
    uint8_t* w = (uint8_t*)d_ws;
    size_t o_x8   = take((size_t)NN * 128);
    size_t o_sc0  = take((size_t)NN * 4);
    size_t o_g0   = take((size_t)NN * 128 * 2);
    size_t o_bufP = take((size_t)NN * 256 * 2);
    size_t o_y8a  = take((size_t)NN * 256);
    size_t o_y8b  = take((size_t)NN * 256);
    size_t o_scA  = take((size_t)NN * 2 * 4);
    size_t o_scB  = take((size_t)NN * 2 * 4);
    size_t o_wf   = take((size_t)12 * MAT_STRIDE * 2);
    size_t o_col  = take((size_t)NBUCK * BCAP * 4);
    size_t o_part = take((size_t)NBUCK * BCAP * 4);
    size_t o_rowpair = take((size_t)NN * 8);
    size_t o_coef = take((size_t)3 * 2 * 256 * 4);
    size_t zero_begin = o;
    size_t o_bcnt   = take((size_t)NBUCK * 4);
    size_t o_stats  = take((size_t)6 * NREP * 256 * 4);
    size_t o_cnt    = take(GG * 4);
    size_t o_poolA  = take((size_t)GG * 128 * 4);
    size_t o_poolB  = take((size_t)GG * 128 * 4);
    size_t zero_end = o;

    unsigned short* x8 = (unsigned short*)(w + o_x8);
    float* sc0 = (float*)(w + o_sc0);
    uint32* g0 = (uint32*)(w + o_g0);
    unsigned short* bufP = (unsigned short*)(w + o_bufP);
    unsigned char* y8a = (unsigned char*)(w + o_y8a);
    unsigned char* y8b = (unsigned char*)(w + o_y8b);
    float* scA = (float*)(w + o_scA);
    float* scB = (float*)(w + o_scB);
    unsigned short* wf = (unsigned short*)(w + o_wf);
    int* col = (int*)(w + o_col);
    uint32* part = (uint32*)(w + o_part);
    int2* rowpair = (int2*)(w + o_rowpair);
    float* coef = (float*)(w + o_coef);
    int* bcnt = (int*)(w + o_bcnt);
    float* statsRep = (float*)(w + o_stats);
    float* cnt = (float*)(w + o_cnt);
    float* poolA = (float*)(w + o_poolA);
    float* poolB = (float*)(w + o_poolB);

    hipMemsetAsync(w + zero_begin, 0, zero_end - zero_begin, stream);

    x_to_i8_kernel<<<(NN * 64 + 255) / 256, 256, 0, stream>>>(x, x8, sc0);
    convert_w_kernel<<<(24576 + 255) / 256, 256, 0, stream>>>(W1a, W2a, W1b, W2b, wf);

    partition_kernel<<<(EE + PART_CHUNK - 1) / PART_CHUNK, 256, 0, stream>>>(src, dst, bcnt, part);
    build_col_kernel<<<NBUCK, 256, 0, stream>>>(part, bcnt, col, rowpair);
    counts_kernel<<<(NN + 255) / 256, 256, 0, stream>>>(batch, cnt, NN);

    int gatherBlocks = (NN + 3) / 4;
    dim3 mlpGrid((NN + 63) / 64, 2);
    size_t ldsBytes = (LDS_W1 + LDS_HS) * 2 + 256 * 4;   // 67840+... = 32768+17408+1024 = 51200

    gather0_kernel<<<gatherBlocks, 256, 0, stream>>>((const uint32*)x8, sc0, rowpair, col, (uint2*)g0);

    // layer 0: g0 -> y8a
    mlp0_kernel<<<mlpGrid, 256, ldsBytes, stream>>>(
        (const unsigned short*)g0, wf, b1a, b1b, b2a, b2b, y8a, scA, statsRep, NN);
    bn_coefs_kernel<<<1, 256, 0, stream>>>(statsRep, ga, bta, gb, btb, 0, coef + 0 * 512);

    // layer 1 fused: y8a -> y8b
    fused_layer_kernel<<<mlpGrid, 256, ldsBytes, stream>>>(
        (const uint32*)y8a, scA, rowpair, col, coef + 0 * 512, wf,
        b1a, b1b, b2a, b2b, 1, 1, nullptr, y8b, scB, statsRep, NN);
    bn_coefs_kernel<<<1, 256, 0, stream>>>(statsRep, ga, bta, gb, btb, 1, coef + 1 * 512);

    // layer 2 fused: y8b -> bufP (bf16)
    fused_layer_kernel<<<mlpGrid, 256, ldsBytes, stream>>>(
        (const uint32*)y8b, scB, rowpair, col, coef + 1 * 512, wf,
        b1a, b1b, b2a, b2b, 2, 0, bufP, nullptr, nullptr, statsRep, NN);
    bn_coefs_kernel<<<1, 256, 0, stream>>>(statsRep, ga, bta, gb, btb, 2, coef + 2 * 512);

    pool_dual_kernel<<<(NN + POOL_CHUNK - 1) / POOL_CHUNK, 256, 0, stream>>>(
        bufP, coef + 2 * 512, batch, poolA, poolB, NN);
    disc_kernel<<<GG, 128, 0, stream>>>(poolB, cnt, disc_w, disc_b, out);
    head_kernel<<<GG, 128, 0, stream>>>(poolA, poolB, cnt, lin1_w, lin1_b, lin2_w, lin2_b, out);
}

// Round 9
// 688.347 us; speedup vs baseline: 1.4279x; 1.4279x over previous
//
#include <hip/hip_runtime.h>
#include <hip/hip_bf16.h>

#define NN 100000
#define EE 1600000
#define GG 64
#define HH 128
#define LL 3
#define BN_EPS 1e-5f
#define NBUCK 196          // ceil(NN/512)
#define BCAP 12288         // bucket capacity (mean 8163, +45 sigma safe)
#define PART_CHUNK 8192
#define NREP 16            // stats replicas

typedef __attribute__((ext_vector_type(8))) short bf16x8;
typedef __attribute__((ext_vector_type(4))) float f32x4;
typedef unsigned int uint32;

__device__ __forceinline__ unsigned short f2bf(float f) {
    uint32 x = __float_as_uint(f);
    uint32 r = (x + 0x7fffu + ((x >> 16) & 1u)) >> 16;
    return (unsigned short)r;
}
__device__ __forceinline__ float bf2f(unsigned short u) { return __uint_as_float(((uint32)u) << 16); }
// dequant-accumulate 4 unsigned uint8 channels with per-row scale
__device__ __forceinline__ void accq(float4& a, uint32 u, float sc) {
    a.x += sc * (float)(u & 0xffu);
    a.y += sc * (float)((u >> 8) & 0xffu);
    a.z += sc * (float)((u >> 16) & 0xffu);
    a.w += sc * (float)(u >> 24);
}
// dequant-accumulate 4 signed int8 channels with per-row scale
__device__ __forceinline__ void accqs(float4& a, uint32 u, float sc) {
    a.x += sc * (float)((int)(u << 24) >> 24);
    a.y += sc * (float)((int)(u << 16) >> 24);
    a.z += sc * (float)((int)(u << 8) >> 24);
    a.w += sc * (float)((int)u >> 24);
}

// ---------------- bucketed edge partition ----------------
__global__ __launch_bounds__(256) void partition_kernel(
    const int* __restrict__ src, const int* __restrict__ dst,
    int* __restrict__ bcnt, uint32* __restrict__ part) {
    __shared__ int cnt[NBUCK];
    __shared__ int loff[NBUCK + 1];
    __shared__ int gpos[NBUCK];
    __shared__ int lcur[NBUCK];
    __shared__ uint32 buf[PART_CHUNK];
    int tid = threadIdx.x;
    int base = blockIdx.x * PART_CHUNK;
    int n = min(PART_CHUNK, EE - base);
    for (int i = tid; i < NBUCK; i += 256) { cnt[i] = 0; lcur[i] = 0; }
    __syncthreads();
    for (int i = tid; i < n; i += 256) atomicAdd(&cnt[dst[base + i] >> 9], 1);
    __syncthreads();
    if (tid == 0) {
        int acc = 0;
        for (int b = 0; b < NBUCK; ++b) { loff[b] = acc; acc += cnt[b]; }
        loff[NBUCK] = acc;
    }
    __syncthreads();
    if (tid < NBUCK && cnt[tid] > 0) gpos[tid] = atomicAdd(&bcnt[tid], cnt[tid]);
    __syncthreads();
    for (int i = tid; i < n; i += 256) {
        int d = dst[base + i];
        int s = src[base + i];
        int b = d >> 9;
        int slot = atomicAdd(&lcur[b], 1);
        buf[loff[b] + slot] = (uint32)s | ((uint32)(d & 511) << 17);
    }
    __syncthreads();
    for (int i = tid; i < n; i += 256) {
        int lo = 0, hi = NBUCK;
        while (hi - lo > 1) { int mid = (lo + hi) >> 1; if (loff[mid] <= i) lo = mid; else hi = mid; }
        part[(size_t)lo * BCAP + gpos[lo] + (i - loff[lo])] = buf[i];
    }
}

// ---------------- build per-bucket CSR + col (in LDS) ----------------
__global__ __launch_bounds__(256) void build_col_kernel(
    const uint32* __restrict__ part, const int* __restrict__ bcnt,
    int* __restrict__ col, int2* __restrict__ rowpair) {
    __shared__ int ldeg[512];
    __shared__ int loffn[512];
    __shared__ int lcur[512];
    __shared__ int pscan[256];
    __shared__ int cl[BCAP];
    int b = blockIdx.x;
    int tid = threadIdx.x;
    int node0 = b << 9;
    int nn = min(node0 + 512, NN) - node0;
    int cnt = bcnt[b];
    int base = b * BCAP;
    const uint32* pp = part + (size_t)base;
    for (int i = tid; i < 512; i += 256) { ldeg[i] = 0; lcur[i] = 0; }
    __syncthreads();
    for (int i = tid; i < cnt; i += 256) atomicAdd(&ldeg[pp[i] >> 17], 1);
    __syncthreads();
    int t2 = tid * 2;
    int a0 = ldeg[t2], a1 = ldeg[t2 + 1];
    int ps = a0 + a1;
    pscan[tid] = ps;
    __syncthreads();
    for (int off = 1; off < 256; off <<= 1) {
        int v = (tid >= off) ? pscan[tid - off] : 0;
        __syncthreads();
        pscan[tid] += v;
        __syncthreads();
    }
    int eo = pscan[tid] - ps;
    loffn[t2] = eo;
    loffn[t2 + 1] = eo + a0;
    if (t2 < nn)     rowpair[node0 + t2]     = make_int2(base + eo, base + eo + a0);
    if (t2 + 1 < nn) rowpair[node0 + t2 + 1] = make_int2(base + eo + a0, base + eo + a0 + a1);
    __syncthreads();
    for (int i = tid; i < cnt; i += 256) {
        uint32 v = pp[i];
        int dl = (int)(v >> 17);
        int pos = atomicAdd(&lcur[dl], 1);
        cl[loffn[dl] + pos] = (int)(v & 0x1FFFFu);
    }
    __syncthreads();
    for (int i = tid; i < cnt; i += 256) col[base + i] = cl[i];
}

// ---------------- graph counts ----------------
__global__ void counts_kernel(const int* __restrict__ batch, float* __restrict__ cnt, int n) {
    __shared__ int h[GG];
    int tid = threadIdx.x;
    if (tid < GG) h[tid] = 0;
    __syncthreads();
    int i = blockIdx.x * 256 + tid;
    if (i < n) atomicAdd(&h[batch[i]], 1);
    __syncthreads();
    if (tid < GG && h[tid]) atomicAdd(&cnt[tid], (float)h[tid]);
}

// ---------------- x -> int8 row-quantized ----------------
__global__ void x_to_i8_kernel(const float* __restrict__ x, unsigned short* __restrict__ x8,
                               float* __restrict__ sc0) {
    int row = (blockIdx.x * 256 + threadIdx.x) >> 6;
    int lane = threadIdx.x & 63;
    if (row >= NN) return;
    float2 v = ((const float2*)x)[(size_t)row * 64 + lane];
    float m = fmaxf(fabsf(v.x), fabsf(v.y));
#pragma unroll
    for (int off = 1; off < 64; off <<= 1) m = fmaxf(m, __shfl_xor(m, off));
    float scale = m * (1.f / 127.f);
    float inv = (m > 0.f) ? 127.f / m : 0.f;
    int b0 = __float2int_rn(v.x * inv);
    int b1 = __float2int_rn(v.y * inv);
    unsigned short pk = (unsigned short)((b0 & 0xff) | ((b1 & 0xff) << 8));
    x8[(size_t)row * 64 + lane] = pk;
    if (lane == 0) sc0[row] = scale;
}

#define MAT_STRIDE 16384   // ushort elements per frag-ordered matrix

// frag-order weights: [br(2)][l(3)][mat(2)][nt(8)][ks(4)][lane(64)][j(8)]
__global__ void convert_w_kernel(const float* __restrict__ W1a, const float* __restrict__ W2a,
                                 const float* __restrict__ W1b, const float* __restrict__ W2b,
                                 unsigned short* __restrict__ out) {
    int t = blockIdx.x * 256 + threadIdx.x;
    if (t >= 24576) return;
    int lane = t & 63;
    int r = t >> 6;
    int ks = r & 3; r >>= 2;
    int nt = r & 7; r >>= 3;
    int mat = r & 1; r >>= 1;
    int l = r % 3, br = r / 3;
    const float* W = br ? (mat ? W2b : W1b) : (mat ? W2a : W1a);
    const float* Wl = W + (size_t)l * 128 * 128;
    int n0 = nt * 16 + (lane & 15);
    int k0 = ks * 32 + (lane >> 4) * 8;
    unsigned short tmp[8];
#pragma unroll
    for (int j = 0; j < 8; ++j) tmp[j] = f2bf(Wl[(size_t)(k0 + j) * 128 + n0]);
    size_t seq = (size_t)(br * 3 + l) * 2 + mat;
    size_t off = (((seq * 8 + nt) * 4 + ks) * 64 + (size_t)lane) * 8;
    *(uint4*)(out + off) = *(const uint4*)tmp;
}

// ---------------- BN coefs from replicated stats ----------------
__global__ void bn_coefs_kernel(const float* __restrict__ statsRep,
                                const float* __restrict__ ga, const float* __restrict__ bta,
                                const float* __restrict__ gb, const float* __restrict__ btb,
                                int l, float* __restrict__ coef) {
    int t = threadIdx.x;        // 256: br*128+cc
    int br = t >> 7, cc = t & 127;
    const float* base = statsRep + (size_t)((l * 2 + br) * NREP) * 256;
    float s = 0.f, sq = 0.f;
#pragma unroll
    for (int rep = 0; rep < NREP; ++rep) {
        s += base[rep * 256 + cc];
        sq += base[rep * 256 + 128 + cc];
    }
    float mu = s * (1.f / NN);
    float var = sq * (1.f / NN) - mu * mu;
    float gm = (br ? gb : ga)[l * 128 + cc];
    float A = gm * rsqrtf(var + BN_EPS);
    float B = (br ? btb : bta)[l * 128 + cc] - mu * A;
    coef[br * 256 + cc] = A;
    coef[br * 256 + 128 + cc] = B;
}

// ---------------- layer-0 gather on int8 x ----------------
__global__ void gather0_kernel(const uint32* __restrict__ x8, const float* __restrict__ sc0,
                               const int2* __restrict__ rowpair, const int* __restrict__ col,
                               uint2* __restrict__ out) {
    int gw = (blockIdx.x * blockDim.x + threadIdx.x) >> 6;
    int lane = threadIdx.x & 63;
    if (gw >= NN) return;
    int slot = lane >> 5;
    int c = lane & 31;
    float4 acc = {0.f, 0.f, 0.f, 0.f};
    if (slot == 0) accqs(acc, x8[(size_t)gw * 32 + c], sc0[gw]);
    int2 be = rowpair[gw];
    int beg = be.x, end = be.y;
    int e = beg;
    for (; e + 4 <= end; e += 4) {
        int j0 = col[e + slot], j1 = col[e + 2 + slot];
        uint32 u0 = x8[(size_t)j0 * 32 + c]; float s0 = sc0[j0];
        uint32 u1 = x8[(size_t)j1 * 32 + c]; float s1 = sc0[j1];
        accqs(acc, u0, s0);
        accqs(acc, u1, s1);
    }
    for (; e + 2 <= end; e += 2) {
        int j = col[e + slot];
        accqs(acc, x8[(size_t)j * 32 + c], sc0[j]);
    }
    if (e < end && slot == 0) {
        int j = col[e];
        accqs(acc, x8[(size_t)j * 32 + c], sc0[j]);
    }
    acc.x += __shfl_xor(acc.x, 32);
    acc.y += __shfl_xor(acc.y, 32);
    acc.z += __shfl_xor(acc.z, 32);
    acc.w += __shfl_xor(acc.w, 32);
    if (slot == 0) {
        uint2 o;
        o.x = (uint32)f2bf(acc.x) | ((uint32)f2bf(acc.y) << 16);
        o.y = (uint32)f2bf(acc.z) | ((uint32)f2bf(acc.w) << 16);
        out[(size_t)gw * 32 + c] = o;
    }
}

// ---------------- dual-branch gather on uint8 concat [N,256] rows (coefs precomputed) -------
__global__ void gather_dual_kernel(const uint32* __restrict__ y8, const float* __restrict__ scales,
                                   const int2* __restrict__ rowpair, const int* __restrict__ col,
                                   const float* __restrict__ coef, uint2* __restrict__ out) {
    int gw = (blockIdx.x * blockDim.x + threadIdx.x) >> 6;
    int lane = threadIdx.x & 63;
    if (gw >= NN) return;
    int br = lane >> 5;
    int c32 = lane & 31;
    float4 A4 = ((const float4*)(coef + br * 256))[c32];
    float4 B4 = ((const float4*)(coef + br * 256 + 128))[c32];
    float4 accA = {0.f, 0.f, 0.f, 0.f};
    float4 accB = {0.f, 0.f, 0.f, 0.f};
    {
        uint32 us = y8[(size_t)gw * 64 + lane];
        accq(accA, us, scales[gw * 2 + br]);
    }
    int2 be = rowpair[gw];
    int beg = be.x, end = be.y;
    float degp1 = (float)(end - beg + 1);
    int e = beg;
    for (; e + 4 <= end; e += 4) {
        int j0 = col[e], j1 = col[e + 1], j2 = col[e + 2], j3 = col[e + 3];
        uint32 u0 = y8[(size_t)j0 * 64 + lane]; float s0 = scales[j0 * 2 + br];
        uint32 u1 = y8[(size_t)j1 * 64 + lane]; float s1 = scales[j1 * 2 + br];
        uint32 u2 = y8[(size_t)j2 * 64 + lane]; float s2 = scales[j2 * 2 + br];
        uint32 u3 = y8[(size_t)j3 * 64 + lane]; float s3 = scales[j3 * 2 + br];
        accq(accA, u0, s0);
        accq(accB, u1, s1);
        accq(accA, u2, s2);
        accq(accB, u3, s3);
    }
    for (; e < end; ++e) {
        int j = col[e];
        accq(accA, y8[(size_t)j * 64 + lane], scales[j * 2 + br]);
    }
    float o0 = A4.x * (accA.x + accB.x) + B4.x * degp1;
    float o1 = A4.y * (accA.y + accB.y) + B4.y * degp1;
    float o2 = A4.z * (accA.z + accB.z) + B4.z * degp1;
    float o3 = A4.w * (accA.w + accB.w) + B4.w * degp1;
    uint2 o;
    o.x = (uint32)f2bf(o0) | ((uint32)f2bf(o1) << 16);
    o.y = (uint32)f2bf(o2) | ((uint32)f2bf(o3) << 16);
    out[(size_t)gw * 64 + lane] = o;
}

// ---------------- fused dual-branch MLP: 512 threads, 8 waves share one W1 LDS stage --------
// blockIdx.y = branch; 128 rows/block. quant=1: uint8+scale out; quant=0: bf16 concat out.
// dynamic LDS: w1s[16384 us] | hs[8][16][136] | ssum[128] | ssq[128]  = 68608 B (2 blocks/CU)
#define LDS_W1 16384
#define LDS_HS (8 * 16 * 136)
__global__ __launch_bounds__(512, 4) void mlp_dual_kernel(
    const unsigned short* __restrict__ X, int in_stride, int in_off_mul,
    const unsigned short* __restrict__ wf_all,
    const float* __restrict__ b1a, const float* __restrict__ b1b,
    const float* __restrict__ b2a, const float* __restrict__ b2b,
    int l, int quant,
    unsigned short* __restrict__ Y, unsigned char* __restrict__ Y8,
    float* __restrict__ scales, float* __restrict__ statsRep, int n) {
    extern __shared__ unsigned short lds_all[];
    unsigned short* w1s = lds_all;
    unsigned short (*hs)[16][136] = (unsigned short (*)[16][136])(lds_all + LDS_W1);
    float* ssum = (float*)(lds_all + LDS_W1 + LDS_HS);
    float* ssq = ssum + 128;

    int br = blockIdx.y;
    const unsigned short* Wf = wf_all + (size_t)(br * 3 + l) * 2 * MAT_STRIDE;
    const float* b1 = (br ? b1b : b1a) + l * 128;
    const float* b2 = (br ? b2b : b2a) + l * 128;
    float* statsp = statsRep + (size_t)((l * 2 + br) * NREP + (blockIdx.x & (NREP - 1))) * 256;
    int in_off = in_off_mul * br;

    int tid = threadIdx.x;
    int wv = tid >> 6, lane = tid & 63;
    int quad = lane >> 4, l16 = lane & 15;

    const bf16x8* w2g = (const bf16x8*)(Wf + MAT_STRIDE);

    // early W2 prefetch (nt=0,1) — overlaps the W1 stage + GEMM1
    bf16x8 w2p[2][4];
#pragma unroll
    for (int p = 0; p < 2; ++p)
#pragma unroll
        for (int ks = 0; ks < 4; ++ks) w2p[p][ks] = w2g[(p * 4 + ks) * 64 + lane];

    int row0 = blockIdx.x * 128 + wv * 16;

    // early A-fragment loads (independent of LDS)
    bf16x8 aF[4];
    {
        int r = row0 + l16;
        if (r >= n) r = n - 1;
        const unsigned short* xrow = X + (size_t)r * in_stride + in_off;
#pragma unroll
        for (int ks = 0; ks < 4; ++ks) aF[ks] = *(const bf16x8*)(xrow + ks * 32 + quad * 8);
    }

    // cooperative W1 stage (2048 uint4 / 512 threads)
    {
        const uint4* srcp = (const uint4*)Wf;
        uint4* dstp = (uint4*)w1s;
        for (int i = tid; i < 2048; i += 512) dstp[i] = srcp[i];
    }
    if (tid < 128) { ssum[tid] = 0.f; ssq[tid] = 0.f; }
    __syncthreads();

    f32x4 acc1[8];
#pragma unroll
    for (int nt = 0; nt < 8; ++nt) {
        f32x4 c = {0.f, 0.f, 0.f, 0.f};
#pragma unroll
        for (int ks = 0; ks < 4; ++ks) {
            bf16x8 bfrag = *(const bf16x8*)(&w1s[((nt * 4 + ks) * 64 + lane) * 8]);
            c = __builtin_amdgcn_mfma_f32_16x16x32_bf16(aF[ks], bfrag, c, 0, 0, 0);
        }
        acc1[nt] = c;
    }

#pragma unroll
    for (int nt = 0; nt < 8; ++nt) {
        int c0 = nt * 16 + l16;
        float bb = b1[c0];
#pragma unroll
        for (int r = 0; r < 4; ++r) {
            float v = fmaxf(acc1[nt][r] + bb, 0.f);
            hs[wv][quad * 4 + r][c0] = f2bf(v);
        }
    }

    bf16x8 aH[4];
#pragma unroll
    for (int ks = 0; ks < 4; ++ks)
        aH[ks] = *(const bf16x8*)(&hs[wv][l16][ks * 32 + quad * 8]);

    f32x4 acc2_[8];
#pragma unroll
    for (int nt = 0; nt < 8; ++nt) {
        bf16x8 bf0, bf1, bf2, bf3;
        if (nt < 2) { bf0 = w2p[nt][0]; bf1 = w2p[nt][1]; bf2 = w2p[nt][2]; bf3 = w2p[nt][3]; }
        else {
            bf0 = w2g[(nt * 4 + 0) * 64 + lane];
            bf1 = w2g[(nt * 4 + 1) * 64 + lane];
            bf2 = w2g[(nt * 4 + 2) * 64 + lane];
            bf3 = w2g[(nt * 4 + 3) * 64 + lane];
        }
        f32x4 c = {0.f, 0.f, 0.f, 0.f};
        c = __builtin_amdgcn_mfma_f32_16x16x32_bf16(aH[0], bf0, c, 0, 0, 0);
        c = __builtin_amdgcn_mfma_f32_16x16x32_bf16(aH[1], bf1, c, 0, 0, 0);
        c = __builtin_amdgcn_mfma_f32_16x16x32_bf16(aH[2], bf2, c, 0, 0, 0);
        c = __builtin_amdgcn_mfma_f32_16x16x32_bf16(aH[3], bf3, c, 0, 0, 0);
        acc2_[nt] = c;
    }

    // bias2 + relu + OOB-zero + BN stats
#pragma unroll
    for (int nt = 0; nt < 8; ++nt) {
        int c0 = nt * 16 + l16;
        float bb = b2[c0];
        float s = 0.f, sq = 0.f;
#pragma unroll
        for (int r = 0; r < 4; ++r) {
            float v = fmaxf(acc2_[nt][r] + bb, 0.f);
            if (row0 + quad * 4 + r >= n) v = 0.f;
            acc2_[nt][r] = v;
            s += v; sq += v * v;
        }
        s += __shfl_xor(s, 16); s += __shfl_xor(s, 32);
        sq += __shfl_xor(sq, 16); sq += __shfl_xor(sq, 32);
        if (quad == 0) { atomicAdd(&ssum[c0], s); atomicAdd(&ssq[c0], sq); }
    }

    unsigned char* hs8 = (unsigned char*)&hs[wv][0][0];
    if (!quant) {
#pragma unroll
        for (int nt = 0; nt < 8; ++nt) {
            int c0 = nt * 16 + l16;
#pragma unroll
            for (int r = 0; r < 4; ++r) hs[wv][quad * 4 + r][c0] = f2bf(acc2_[nt][r]);
        }
        int grow = row0 + l16;
        if (grow < n) {
#pragma unroll
            for (int j = 0; j < 4; ++j) {
                uint4 v = *(const uint4*)(&hs[wv][l16][quad * 32 + j * 8]);
                *(uint4*)(Y + (size_t)grow * 256 + br * 128 + quad * 32 + j * 8) = v;
            }
        }
    } else {
#pragma unroll
        for (int r = 0; r < 4; ++r) {
            float m = acc2_[0][r];
#pragma unroll
            for (int nt = 1; nt < 8; ++nt) m = fmaxf(m, acc2_[nt][r]);
            m = fmaxf(m, __shfl_xor(m, 1));
            m = fmaxf(m, __shfl_xor(m, 2));
            m = fmaxf(m, __shfl_xor(m, 4));
            m = fmaxf(m, __shfl_xor(m, 8));
            float sc = m * (1.f / 255.f);
            float inv = (m > 0.f) ? 255.f / m : 0.f;
            int grow = row0 + quad * 4 + r;
            if (l16 == r && grow < n) scales[grow * 2 + br] = sc;
#pragma unroll
            for (int nt = 0; nt < 8; ++nt) {
                uint32 u = (uint32)__float2int_rn(acc2_[nt][r] * inv);
                hs8[(quad * 4 + r) * 144 + nt * 16 + l16] = (unsigned char)u;
            }
        }
        int grow = row0 + l16;
        if (grow < n) {
            *(uint4*)(Y8 + (size_t)grow * 256 + br * 128 + quad * 32) =
                *(const uint4*)(hs8 + l16 * 144 + quad * 32);
            *(uint4*)(Y8 + (size_t)grow * 256 + br * 128 + quad * 32 + 16) =
                *(const uint4*)(hs8 + l16 * 144 + quad * 32 + 16);
        }
    }
    __syncthreads();
    if (tid < 128) {
        atomicAdd(&statsp[tid], ssum[tid]);
        atomicAdd(&statsp[128 + tid], ssq[tid]);
    }
}

// ---------------- dual pooling (coefs precomputed) ----------------
#define POOL_CHUNK 128
__global__ void pool_dual_kernel(const unsigned short* __restrict__ h,
                                 const float* __restrict__ coef2,
                                 const int* __restrict__ batch,
                                 float* __restrict__ poolA, float* __restrict__ poolB, int n) {
    int t = threadIdx.x;
    int br = t >> 7, cc = t & 127;
    float a = coef2[br * 256 + cc];
    float b = coef2[br * 256 + 128 + cc];
    float* pool = br ? poolB : poolA;

    int i0 = blockIdx.x * POOL_CHUNK;
    if (i0 >= n) return;
    int i1 = min(i0 + POOL_CHUNK, n);
    float acc = 0.f;
    int cur = batch[i0];
    for (int i = i0; i < i1; ++i) {
        int g = batch[i];
        if (g != cur) {
            atomicAdd(&pool[cur * 128 + cc], acc);
            acc = 0.f;
            cur = g;
        }
        acc += a * bf2f(h[(size_t)i * 256 + t]) + b;
    }
    atomicAdd(&pool[cur * 128 + cc], acc);
}

// ---------------- bilinear discriminator ----------------
__global__ void disc_kernel(const float* __restrict__ poolB, const float* __restrict__ cnt,
                            const float* __restrict__ W, const float* __restrict__ db,
                            float* __restrict__ out) {
    int g = blockIdx.x, e = threadIdx.x;
    __shared__ float rs[128], rh[128];
    float invc = 1.f / fmaxf(cnt[g], 1.f);
    int gs = (g == 32) ? 30 : (63 - g);
    float invcs = 1.f / fmaxf(cnt[gs], 1.f);
    const float* a = poolB + g * 128;
    float t = 0.f;
    for (int d = 0; d < 128; ++d) t += a[d] * W[d * 128 + e];
    t *= invc;
    rs[e] = t * poolB[g * 128 + e] * invc;
    rh[e] = t * poolB[gs * 128 + e] * invcs;
    __syncthreads();
    for (int s = 64; s > 0; s >>= 1) {
        if (e < s) { rs[e] += rs[e + s]; rh[e] += rh[e + s]; }
        __syncthreads();
    }
    if (e == 0) {
        out[GG * 10 + g] = rs[0] + db[0];
        out[GG * 10 + GG + g] = rh[0] + db[0];
    }
}

// ---------------- classification head ----------------
__global__ void head_kernel(const float* __restrict__ poolA, const float* __restrict__ poolB,
                            const float* __restrict__ cnt,
                            const float* __restrict__ w1, const float* __restrict__ b1,
                            const float* __restrict__ w2, const float* __restrict__ b2,
                            float* __restrict__ out) {
    int g = blockIdx.x, j = threadIdx.x;
    __shared__ float s1[128];
    __shared__ float s2[10];
    __shared__ float lse;
    float invc = 1.f / fmaxf(cnt[g], 1.f);
    const float* ma = poolA + g * 128;
    const float* px = poolB + g * 128;
    float acc = b1[j];
    for (int k = 0; k < 128; ++k) acc += ma[k] * invc * w1[k * 128 + j];
    for (int k = 0; k < 128; ++k) acc += px[k] * invc * w1[(128 + k) * 128 + j];
    s1[j] = fmaxf(acc, 0.f);
    __syncthreads();
    if (j < 10) {
        float a = b2[j];
        for (int k = 0; k < 128; ++k) a += s1[k] * w2[k * 10 + j];
        s2[j] = a;
    }
    __syncthreads();
    if (j == 0) {
        float m = s2[0];
        for (int o = 1; o < 10; ++o) m = fmaxf(m, s2[o]);
        float se = 0.f;
        for (int o = 0; o < 10; ++o) se += expf(s2[o] - m);
        lse = m + logf(se);
    }
    __syncthreads();
    if (j < 10) out[g * 10 + j] = s2[j] - lse;
}

extern "C" void kernel_launch(void* const* d_in, const int* in_sizes, int n_in,
                              void* d_out, int out_size, void* d_ws, size_t ws_size,
                              hipStream_t stream) {
    const float* x     = (const float*)d_in[0];
    const int*   ei    = (const int*)d_in[1];
    const int*   batch = (const int*)d_in[2];
    const float* W1a = (const float*)d_in[3];
    const float* b1a = (const float*)d_in[4];
    const float* W2a = (const float*)d_in[5];
    const float* b2a = (const float*)d_in[6];
    const float* ga  = (const float*)d_in[7];
    const float* bta = (const float*)d_in[8];
    const float* W1b = (const float*)d_in[9];
    const float* b1b = (const float*)d_in[10];
    const float* W2b = (const float*)d_in[11];
    const float* b2b = (const float*)d_in[12];
    const float* gb  = (const float*)d_in[13];
    const float* btb = (const float*)d_in[14];
    const float* lin1_w = (const float*)d_in[15];
    const float* lin1_b = (const float*)d_in[16];
    const float* lin2_w = (const float*)d_in[17];
    const float* lin2_b = (const float*)d_in[18];
    const float* disc_w = (const float*)d_in[19];
    const float* disc_b = (const float*)d_in[20];
    float* out = (float*)d_out;

    const int* src = ei;
    const int* dst = ei + EE;

    size_t o = 0;
    auto take = [&](size_t b) { size_t p = o; o = (o + b + 255) & ~(size_t)255; return p; };
    uint8_t* w = (uint8_t*)d_ws;
    size_t o_x8   = take((size_t)NN * 128);
    size_t o_sc0  = take((size_t)NN * 4);
    size_t o_g0   = take((size_t)NN * 128 * 2);
    size_t o_bufP = take((size_t)NN * 256 * 2);
    size_t o_gbuf = take((size_t)NN * 256 * 2);
    size_t o_y8a  = take((size_t)NN * 256);
    size_t o_y8b  = take((size_t)NN * 256);
    size_t o_scA  = take((size_t)NN * 2 * 4);
    size_t o_scB  = take((size_t)NN * 2 * 4);
    size_t o_wf   = take((size_t)12 * MAT_STRIDE * 2);
    size_t o_col  = take((size_t)NBUCK * BCAP * 4);
    size_t o_part = take((size_t)NBUCK * BCAP * 4);
    size_t o_rowpair = take((size_t)NN * 8);
    size_t o_coef = take((size_t)3 * 2 * 256 * 4);
    size_t zero_begin = o;
    size_t o_bcnt   = take((size_t)NBUCK * 4);
    size_t o_stats  = take((size_t)6 * NREP * 256 * 4);
    size_t o_cnt    = take(GG * 4);
    size_t o_poolA  = take((size_t)GG * 128 * 4);
    size_t o_poolB  = take((size_t)GG * 128 * 4);
    size_t zero_end = o;

    unsigned short* x8 = (unsigned short*)(w + o_x8);
    float* sc0 = (float*)(w + o_sc0);
    uint32* g0 = (uint32*)(w + o_g0);
    unsigned short* bufP = (unsigned short*)(w + o_bufP);
    unsigned short* gbuf = (unsigned short*)(w + o_gbuf);
    unsigned char* y8a = (unsigned char*)(w + o_y8a);
    unsigned char* y8b = (unsigned char*)(w + o_y8b);
    float* scA = (float*)(w + o_scA);
    float* scB = (float*)(w + o_scB);
    unsigned short* wf = (unsigned short*)(w + o_wf);
    int* col = (int*)(w + o_col);
    uint32* part = (uint32*)(w + o_part);
    int2* rowpair = (int2*)(w + o_rowpair);
    float* coef = (float*)(w + o_coef);
    int* bcnt = (int*)(w + o_bcnt);
    float* statsRep = (float*)(w + o_stats);
    float* cnt = (float*)(w + o_cnt);
    float* poolA = (float*)(w + o_poolA);
    float* poolB = (float*)(w + o_poolB);

    hipMemsetAsync(w + zero_begin, 0, zero_end - zero_begin, stream);

    x_to_i8_kernel<<<(NN * 64 + 255) / 256, 256, 0, stream>>>(x, x8, sc0);
    convert_w_kernel<<<(24576 + 255) / 256, 256, 0, stream>>>(W1a, W2a, W1b, W2b, wf);

    partition_kernel<<<(EE + PART_CHUNK - 1) / PART_CHUNK, 256, 0, stream>>>(src, dst, bcnt, part);
    build_col_kernel<<<NBUCK, 256, 0, stream>>>(part, bcnt, col, rowpair);
    counts_kernel<<<(NN + 255) / 256, 256, 0, stream>>>(batch, cnt, NN);

    int gatherBlocks = (NN + 3) / 4;
    dim3 mlpGrid((NN + 127) / 128, 2);
    size_t ldsBytes = (size_t)LDS_W1 * 2 + (size_t)LDS_HS * 2 + 256 * 4;  // 68608

    gather0_kernel<<<gatherBlocks, 256, 0, stream>>>((const uint32*)x8, sc0, rowpair, col, (uint2*)g0);

    // layer 0: g0 -> y8a
    mlp_dual_kernel<<<mlpGrid, 512, ldsBytes, stream>>>(
        (const unsigned short*)g0, 128, 0, wf, b1a, b1b, b2a, b2b, 0, 1,
        nullptr, y8a, scA, statsRep, NN);
    bn_coefs_kernel<<<1, 256, 0, stream>>>(statsRep, ga, bta, gb, btb, 0, coef + 0 * 512);

    // layer 1: gather(y8a) -> gbuf; mlp -> y8b
    gather_dual_kernel<<<gatherBlocks, 256, 0, stream>>>(
        (const uint32*)y8a, scA, rowpair, col, coef + 0 * 512, (uint2*)gbuf);
    mlp_dual_kernel<<<mlpGrid, 512, ldsBytes, stream>>>(
        gbuf, 256, 128, wf, b1a, b1b, b2a, b2b, 1, 1,
        nullptr, y8b, scB, statsRep, NN);
    bn_coefs_kernel<<<1, 256, 0, stream>>>(statsRep, ga, bta, gb, btb, 1, coef + 1 * 512);

    // layer 2: gather(y8b) -> gbuf; mlp -> bufP (bf16)
    gather_dual_kernel<<<gatherBlocks, 256, 0, stream>>>(
        (const uint32*)y8b, scB, rowpair, col, coef + 1 * 512, (uint2*)gbuf);
    mlp_dual_kernel<<<mlpGrid, 512, ldsBytes, stream>>>(
        gbuf, 256, 128, wf, b1a, b1b, b2a, b2b, 2, 0,
        bufP, nullptr, nullptr, statsRep, NN);
    bn_coefs_kernel<<<1, 256, 0, stream>>>(statsRep, ga, bta, gb, btb, 2, coef + 2 * 512);

    pool_dual_kernel<<<(NN + POOL_CHUNK - 1) / POOL_CHUNK, 256, 0, stream>>>(
        bufP, coef + 2 * 512, batch, poolA, poolB, NN);
    disc_kernel<<<GG, 128, 0, stream>>>(poolB, cnt, disc_w, disc_b, out);
    head_kernel<<<GG, 128, 0, stream>>>(poolA, poolB, cnt, lin1_w, lin1_b, lin2_w, lin2_b, out);
}

// Round 10
// 657.531 us; speedup vs baseline: 1.4948x; 1.0469x over previous
//
#include <hip/hip_runtime.h>
#include <hip/hip_bf16.h>

#define NN 100000
#define EE 1600000
#define GG 64
#define HH 128
#define LL 3
#define BN_EPS 1e-5f
#define NBUCK 196          // ceil(NN/512)
#define BCAP 12288         // bucket capacity (mean 8163, +45 sigma safe)
#define PART_CHUNK 8192
#define NREP 16            // stats replicas

typedef __attribute__((ext_vector_type(8))) short bf16x8;
typedef __attribute__((ext_vector_type(4))) float f32x4;
typedef unsigned int uint32;

__device__ __forceinline__ unsigned short f2bf(float f) {
    uint32 x = __float_as_uint(f);
    uint32 r = (x + 0x7fffu + ((x >> 16) & 1u)) >> 16;
    return (unsigned short)r;
}
__device__ __forceinline__ float bf2f(unsigned short u) { return __uint_as_float(((uint32)u) << 16); }
// dequant-accumulate 4 unsigned uint8 channels with per-row scale
__device__ __forceinline__ void accq(float4& a, uint32 u, float sc) {
    a.x += sc * (float)(u & 0xffu);
    a.y += sc * (float)((u >> 8) & 0xffu);
    a.z += sc * (float)((u >> 16) & 0xffu);
    a.w += sc * (float)(u >> 24);
}
// dequant-accumulate 4 signed int8 channels with per-row scale
__device__ __forceinline__ void accqs(float4& a, uint32 u, float sc) {
    a.x += sc * (float)((int)(u << 24) >> 24);
    a.y += sc * (float)((int)(u << 16) >> 24);
    a.z += sc * (float)((int)(u << 8) >> 24);
    a.w += sc * (float)((int)u >> 24);
}

// ---------------- bucketed edge partition ----------------
__global__ __launch_bounds__(256) void partition_kernel(
    const int* __restrict__ src, const int* __restrict__ dst,
    int* __restrict__ bcnt, uint32* __restrict__ part) {
    __shared__ int cnt[NBUCK];
    __shared__ int loff[NBUCK + 1];
    __shared__ int gpos[NBUCK];
    __shared__ int lcur[NBUCK];
    __shared__ uint32 buf[PART_CHUNK];
    int tid = threadIdx.x;
    int base = blockIdx.x * PART_CHUNK;
    int n = min(PART_CHUNK, EE - base);
    for (int i = tid; i < NBUCK; i += 256) { cnt[i] = 0; lcur[i] = 0; }
    __syncthreads();
    for (int i = tid; i < n; i += 256) atomicAdd(&cnt[dst[base + i] >> 9], 1);
    __syncthreads();
    if (tid == 0) {
        int acc = 0;
        for (int b = 0; b < NBUCK; ++b) { loff[b] = acc; acc += cnt[b]; }
        loff[NBUCK] = acc;
    }
    __syncthreads();
    if (tid < NBUCK && cnt[tid] > 0) gpos[tid] = atomicAdd(&bcnt[tid], cnt[tid]);
    __syncthreads();
    for (int i = tid; i < n; i += 256) {
        int d = dst[base + i];
        int s = src[base + i];
        int b = d >> 9;
        int slot = atomicAdd(&lcur[b], 1);
        buf[loff[b] + slot] = (uint32)s | ((uint32)(d & 511) << 17);
    }
    __syncthreads();
    for (int i = tid; i < n; i += 256) {
        int lo = 0, hi = NBUCK;
        while (hi - lo > 1) { int mid = (lo + hi) >> 1; if (loff[mid] <= i) lo = mid; else hi = mid; }
        part[(size_t)lo * BCAP + gpos[lo] + (i - loff[lo])] = buf[i];
    }
}

// ---------------- build per-bucket CSR + col (in LDS) ----------------
__global__ __launch_bounds__(256) void build_col_kernel(
    const uint32* __restrict__ part, const int* __restrict__ bcnt,
    int* __restrict__ col, int2* __restrict__ rowpair) {
    __shared__ int ldeg[512];
    __shared__ int loffn[512];
    __shared__ int lcur[512];
    __shared__ int pscan[256];
    __shared__ int cl[BCAP];
    int b = blockIdx.x;
    int tid = threadIdx.x;
    int node0 = b << 9;
    int nn = min(node0 + 512, NN) - node0;
    int cnt = bcnt[b];
    int base = b * BCAP;
    const uint32* pp = part + (size_t)base;
    for (int i = tid; i < 512; i += 256) { ldeg[i] = 0; lcur[i] = 0; }
    __syncthreads();
    for (int i = tid; i < cnt; i += 256) atomicAdd(&ldeg[pp[i] >> 17], 1);
    __syncthreads();
    int t2 = tid * 2;
    int a0 = ldeg[t2], a1 = ldeg[t2 + 1];
    int ps = a0 + a1;
    pscan[tid] = ps;
    __syncthreads();
    for (int off = 1; off < 256; off <<= 1) {
        int v = (tid >= off) ? pscan[tid - off] : 0;
        __syncthreads();
        pscan[tid] += v;
        __syncthreads();
    }
    int eo = pscan[tid] - ps;
    loffn[t2] = eo;
    loffn[t2 + 1] = eo + a0;
    if (t2 < nn)     rowpair[node0 + t2]     = make_int2(base + eo, base + eo + a0);
    if (t2 + 1 < nn) rowpair[node0 + t2 + 1] = make_int2(base + eo + a0, base + eo + a0 + a1);
    __syncthreads();
    for (int i = tid; i < cnt; i += 256) {
        uint32 v = pp[i];
        int dl = (int)(v >> 17);
        int pos = atomicAdd(&lcur[dl], 1);
        cl[loffn[dl] + pos] = (int)(v & 0x1FFFFu);
    }
    __syncthreads();
    for (int i = tid; i < cnt; i += 256) col[base + i] = cl[i];
}

// ---------------- graph counts ----------------
__global__ void counts_kernel(const int* __restrict__ batch, float* __restrict__ cnt, int n) {
    __shared__ int h[GG];
    int tid = threadIdx.x;
    if (tid < GG) h[tid] = 0;
    __syncthreads();
    int i = blockIdx.x * 256 + tid;
    if (i < n) atomicAdd(&h[batch[i]], 1);
    __syncthreads();
    if (tid < GG && h[tid]) atomicAdd(&cnt[tid], (float)h[tid]);
}

// ---------------- x -> int8 row-quantized ----------------
__global__ void x_to_i8_kernel(const float* __restrict__ x, unsigned short* __restrict__ x8,
                               float* __restrict__ sc0) {
    int row = (blockIdx.x * 256 + threadIdx.x) >> 6;
    int lane = threadIdx.x & 63;
    if (row >= NN) return;
    float2 v = ((const float2*)x)[(size_t)row * 64 + lane];
    float m = fmaxf(fabsf(v.x), fabsf(v.y));
#pragma unroll
    for (int off = 1; off < 64; off <<= 1) m = fmaxf(m, __shfl_xor(m, off));
    float scale = m * (1.f / 127.f);
    float inv = (m > 0.f) ? 127.f / m : 0.f;
    int b0 = __float2int_rn(v.x * inv);
    int b1 = __float2int_rn(v.y * inv);
    unsigned short pk = (unsigned short)((b0 & 0xff) | ((b1 & 0xff) << 8));
    x8[(size_t)row * 64 + lane] = pk;
    if (lane == 0) sc0[row] = scale;
}

#define MAT_STRIDE 16384   // ushort elements per frag-ordered matrix

// frag-order weights: [br(2)][l(3)][mat(2)][nt(8)][ks(4)][lane(64)][j(8)]
__global__ void convert_w_kernel(const float* __restrict__ W1a, const float* __restrict__ W2a,
                                 const float* __restrict__ W1b, const float* __restrict__ W2b,
                                 unsigned short* __restrict__ out) {
    int t = blockIdx.x * 256 + threadIdx.x;
    if (t >= 24576) return;
    int lane = t & 63;
    int r = t >> 6;
    int ks = r & 3; r >>= 2;
    int nt = r & 7; r >>= 3;
    int mat = r & 1; r >>= 1;
    int l = r % 3, br = r / 3;
    const float* W = br ? (mat ? W2b : W1b) : (mat ? W2a : W1a);
    const float* Wl = W + (size_t)l * 128 * 128;
    int n0 = nt * 16 + (lane & 15);
    int k0 = ks * 32 + (lane >> 4) * 8;
    unsigned short tmp[8];
#pragma unroll
    for (int j = 0; j < 8; ++j) tmp[j] = f2bf(Wl[(size_t)(k0 + j) * 128 + n0]);
    size_t seq = (size_t)(br * 3 + l) * 2 + mat;
    size_t off = (((seq * 8 + nt) * 4 + ks) * 64 + (size_t)lane) * 8;
    *(uint4*)(out + off) = *(const uint4*)tmp;
}

// ---------------- BN coefs from replicated stats ----------------
__global__ void bn_coefs_kernel(const float* __restrict__ statsRep,
                                const float* __restrict__ ga, const float* __restrict__ bta,
                                const float* __restrict__ gb, const float* __restrict__ btb,
                                int l, float* __restrict__ coef) {
    int t = threadIdx.x;        // 256: br*128+cc
    int br = t >> 7, cc = t & 127;
    const float* base = statsRep + (size_t)((l * 2 + br) * NREP) * 256;
    float s = 0.f, sq = 0.f;
#pragma unroll
    for (int rep = 0; rep < NREP; ++rep) {
        s += base[rep * 256 + cc];
        sq += base[rep * 256 + 128 + cc];
    }
    float mu = s * (1.f / NN);
    float var = sq * (1.f / NN) - mu * mu;
    float gm = (br ? gb : ga)[l * 128 + cc];
    float A = gm * rsqrtf(var + BN_EPS);
    float B = (br ? btb : bta)[l * 128 + cc] - mu * A;
    coef[br * 256 + cc] = A;
    coef[br * 256 + 128 + cc] = B;
}

// ---------------- layer-0 gather on int8 x (batched col broadcast) ----------------
__global__ void gather0_kernel(const uint32* __restrict__ x8, const float* __restrict__ sc0,
                               const int2* __restrict__ rowpair, const int* __restrict__ col,
                               uint2* __restrict__ out) {
    int gw = (blockIdx.x * blockDim.x + threadIdx.x) >> 6;
    int lane = threadIdx.x & 63;
    if (gw >= NN) return;
    int slot = lane >> 5;
    int c = lane & 31;
    float4 accA = {0.f, 0.f, 0.f, 0.f};
    float4 accB = {0.f, 0.f, 0.f, 0.f};
    if (slot == 0) accqs(accA, x8[(size_t)gw * 32 + c], sc0[gw]);
    int2 be = rowpair[gw];
    int beg = be.x, end = be.y;
    for (int base = beg; base < end; base += 64) {
        int nb = min(64, end - base);
        int colv = col[base + min(lane, nb - 1)];
        int k = 0;
        for (; k + 4 <= nb; k += 4) {
            int j0 = __shfl(colv, k + slot);
            int j1 = __shfl(colv, k + 2 + slot);
            float s0 = sc0[j0], s1 = sc0[j1];
            uint32 u0 = x8[(size_t)j0 * 32 + c];
            uint32 u1 = x8[(size_t)j1 * 32 + c];
            accqs(accA, u0, s0);
            accqs(accB, u1, s1);
        }
        for (; k + 2 <= nb; k += 2) {
            int j = __shfl(colv, k + slot);
            accqs(accA, x8[(size_t)j * 32 + c], sc0[j]);
        }
        if (k < nb) {
            int j = __shfl(colv, k);
            if (slot == 0) accqs(accA, x8[(size_t)j * 32 + c], sc0[j]);
        }
    }
    accA.x += accB.x; accA.y += accB.y; accA.z += accB.z; accA.w += accB.w;
    accA.x += __shfl_xor(accA.x, 32);
    accA.y += __shfl_xor(accA.y, 32);
    accA.z += __shfl_xor(accA.z, 32);
    accA.w += __shfl_xor(accA.w, 32);
    if (slot == 0) {
        uint2 o;
        o.x = (uint32)f2bf(accA.x) | ((uint32)f2bf(accA.y) << 16);
        o.y = (uint32)f2bf(accA.z) | ((uint32)f2bf(accA.w) << 16);
        out[(size_t)gw * 32 + c] = o;
    }
}

// ---------------- dual-branch gather: scalarized col/scale path ----------------
// colv batch (1 VMEM per <=64 edges); readlane -> SGPR j -> s_load scales, SGPR-base row load.
__global__ void gather_dual_kernel(const uint32* __restrict__ y8, const float* __restrict__ scales,
                                   const int2* __restrict__ rowpair, const int* __restrict__ col,
                                   const float* __restrict__ coef, uint2* __restrict__ out) {
    int gw = (blockIdx.x * blockDim.x + threadIdx.x) >> 6;
    int lane = threadIdx.x & 63;
    if (gw >= NN) return;
    int br = lane >> 5;
    int c32 = lane & 31;
    float4 A4 = ((const float4*)(coef + br * 256))[c32];
    float4 B4 = ((const float4*)(coef + br * 256 + 128))[c32];
    float4 accA = {0.f, 0.f, 0.f, 0.f};
    float4 accB = {0.f, 0.f, 0.f, 0.f};
    {
        uint32 us = y8[(size_t)gw * 64 + lane];
        accq(accA, us, scales[gw * 2 + br]);
    }
    int2 be = rowpair[gw];
    int beg = be.x, end = be.y;
    float degp1 = (float)(end - beg + 1);
    const float2* sc2 = (const float2*)scales;
    for (int base = beg; base < end; base += 64) {
        int nb = min(64, end - base);
        int colv = col[base + min(lane, nb - 1)];
        int k = 0;
        for (; k + 4 <= nb; k += 4) {
            int j0 = __builtin_amdgcn_readlane(colv, k);
            int j1 = __builtin_amdgcn_readlane(colv, k + 1);
            int j2 = __builtin_amdgcn_readlane(colv, k + 2);
            int j3 = __builtin_amdgcn_readlane(colv, k + 3);
            float2 s0 = sc2[j0];
            float2 s1 = sc2[j1];
            float2 s2 = sc2[j2];
            float2 s3 = sc2[j3];
            uint32 u0 = y8[(size_t)j0 * 64 + lane];
            uint32 u1 = y8[(size_t)j1 * 64 + lane];
            uint32 u2 = y8[(size_t)j2 * 64 + lane];
            uint32 u3 = y8[(size_t)j3 * 64 + lane];
            accq(accA, u0, br ? s0.y : s0.x);
            accq(accB, u1, br ? s1.y : s1.x);
            accq(accA, u2, br ? s2.y : s2.x);
            accq(accB, u3, br ? s3.y : s3.x);
        }
        for (; k < nb; ++k) {
            int j = __builtin_amdgcn_readlane(colv, k);
            float2 s = sc2[j];
            accq(accA, y8[(size_t)j * 64 + lane], br ? s.y : s.x);
        }
    }
    float o0 = A4.x * (accA.x + accB.x) + B4.x * degp1;
    float o1 = A4.y * (accA.y + accB.y) + B4.y * degp1;
    float o2 = A4.z * (accA.z + accB.z) + B4.z * degp1;
    float o3 = A4.w * (accA.w + accB.w) + B4.w * degp1;
    uint2 o;
    o.x = (uint32)f2bf(o0) | ((uint32)f2bf(o1) << 16);
    o.y = (uint32)f2bf(o2) | ((uint32)f2bf(o3) << 16);
    out[(size_t)gw * 64 + lane] = o;
}

// ---------------- fused dual-branch MLP: 512 threads, 8 waves share one W1 LDS stage --------
#define LDS_W1 16384
#define LDS_HS (8 * 16 * 136)
__global__ __launch_bounds__(512, 4) void mlp_dual_kernel(
    const unsigned short* __restrict__ X, int in_stride, int in_off_mul,
    const unsigned short* __restrict__ wf_all,
    const float* __restrict__ b1a, const float* __restrict__ b1b,
    const float* __restrict__ b2a, const float* __restrict__ b2b,
    int l, int quant,
    unsigned short* __restrict__ Y, unsigned char* __restrict__ Y8,
    float* __restrict__ scales, float* __restrict__ statsRep, int n) {
    extern __shared__ unsigned short lds_all[];
    unsigned short* w1s = lds_all;
    unsigned short (*hs)[16][136] = (unsigned short (*)[16][136])(lds_all + LDS_W1);
    float* ssum = (float*)(lds_all + LDS_W1 + LDS_HS);
    float* ssq = ssum + 128;

    int br = blockIdx.y;
    const unsigned short* Wf = wf_all + (size_t)(br * 3 + l) * 2 * MAT_STRIDE;
    const float* b1 = (br ? b1b : b1a) + l * 128;
    const float* b2 = (br ? b2b : b2a) + l * 128;
    float* statsp = statsRep + (size_t)((l * 2 + br) * NREP + (blockIdx.x & (NREP - 1))) * 256;
    int in_off = in_off_mul * br;

    int tid = threadIdx.x;
    int wv = tid >> 6, lane = tid & 63;
    int quad = lane >> 4, l16 = lane & 15;

    const bf16x8* w2g = (const bf16x8*)(Wf + MAT_STRIDE);

    bf16x8 w2p[2][4];
#pragma unroll
    for (int p = 0; p < 2; ++p)
#pragma unroll
        for (int ks = 0; ks < 4; ++ks) w2p[p][ks] = w2g[(p * 4 + ks) * 64 + lane];

    int row0 = blockIdx.x * 128 + wv * 16;

    bf16x8 aF[4];
    {
        int r = row0 + l16;
        if (r >= n) r = n - 1;
        const unsigned short* xrow = X + (size_t)r * in_stride + in_off;
#pragma unroll
        for (int ks = 0; ks < 4; ++ks) aF[ks] = *(const bf16x8*)(xrow + ks * 32 + quad * 8);
    }

    {
        const uint4* srcp = (const uint4*)Wf;
        uint4* dstp = (uint4*)w1s;
        for (int i = tid; i < 2048; i += 512) dstp[i] = srcp[i];
    }
    if (tid < 128) { ssum[tid] = 0.f; ssq[tid] = 0.f; }
    __syncthreads();

    f32x4 acc1[8];
#pragma unroll
    for (int nt = 0; nt < 8; ++nt) {
        f32x4 c = {0.f, 0.f, 0.f, 0.f};
#pragma unroll
        for (int ks = 0; ks < 4; ++ks) {
            bf16x8 bfrag = *(const bf16x8*)(&w1s[((nt * 4 + ks) * 64 + lane) * 8]);
            c = __builtin_amdgcn_mfma_f32_16x16x32_bf16(aF[ks], bfrag, c, 0, 0, 0);
        }
        acc1[nt] = c;
    }

#pragma unroll
    for (int nt = 0; nt < 8; ++nt) {
        int c0 = nt * 16 + l16;
        float bb = b1[c0];
#pragma unroll
        for (int r = 0; r < 4; ++r) {
            float v = fmaxf(acc1[nt][r] + bb, 0.f);
            hs[wv][quad * 4 + r][c0] = f2bf(v);
        }
    }

    bf16x8 aH[4];
#pragma unroll
    for (int ks = 0; ks < 4; ++ks)
        aH[ks] = *(const bf16x8*)(&hs[wv][l16][ks * 32 + quad * 8]);

    f32x4 acc2_[8];
#pragma unroll
    for (int nt = 0; nt < 8; ++nt) {
        bf16x8 bf0, bf1, bf2, bf3;
        if (nt < 2) { bf0 = w2p[nt][0]; bf1 = w2p[nt][1]; bf2 = w2p[nt][2]; bf3 = w2p[nt][3]; }
        else {
            bf0 = w2g[(nt * 4 + 0) * 64 + lane];
            bf1 = w2g[(nt * 4 + 1) * 64 + lane];
            bf2 = w2g[(nt * 4 + 2) * 64 + lane];
            bf3 = w2g[(nt * 4 + 3) * 64 + lane];
        }
        f32x4 c = {0.f, 0.f, 0.f, 0.f};
        c = __builtin_amdgcn_mfma_f32_16x16x32_bf16(aH[0], bf0, c, 0, 0, 0);
        c = __builtin_amdgcn_mfma_f32_16x16x32_bf16(aH[1], bf1, c, 0, 0, 0);
        c = __builtin_amdgcn_mfma_f32_16x16x32_bf16(aH[2], bf2, c, 0, 0, 0);
        c = __builtin_amdgcn_mfma_f32_16x16x32_bf16(aH[3], bf3, c, 0, 0, 0);
        acc2_[nt] = c;
    }

#pragma unroll
    for (int nt = 0; nt < 8; ++nt) {
        int c0 = nt * 16 + l16;
        float bb = b2[c0];
        float s = 0.f, sq = 0.f;
#pragma unroll
        for (int r = 0; r < 4; ++r) {
            float v = fmaxf(acc2_[nt][r] + bb, 0.f);
            if (row0 + quad * 4 + r >= n) v = 0.f;
            acc2_[nt][r] = v;
            s += v; sq += v * v;
        }
        s += __shfl_xor(s, 16); s += __shfl_xor(s, 32);
        sq += __shfl_xor(sq, 16); sq += __shfl_xor(sq, 32);
        if (quad == 0) { atomicAdd(&ssum[c0], s); atomicAdd(&ssq[c0], sq); }
    }

    unsigned char* hs8 = (unsigned char*)&hs[wv][0][0];
    if (!quant) {
#pragma unroll
        for (int nt = 0; nt < 8; ++nt) {
            int c0 = nt * 16 + l16;
#pragma unroll
            for (int r = 0; r < 4; ++r) hs[wv][quad * 4 + r][c0] = f2bf(acc2_[nt][r]);
        }
        int grow = row0 + l16;
        if (grow < n) {
#pragma unroll
            for (int j = 0; j < 4; ++j) {
                uint4 v = *(const uint4*)(&hs[wv][l16][quad * 32 + j * 8]);
                *(uint4*)(Y + (size_t)grow * 256 + br * 128 + quad * 32 + j * 8) = v;
            }
        }
    } else {
#pragma unroll
        for (int r = 0; r < 4; ++r) {
            float m = acc2_[0][r];
#pragma unroll
            for (int nt = 1; nt < 8; ++nt) m = fmaxf(m, acc2_[nt][r]);
            m = fmaxf(m, __shfl_xor(m, 1));
            m = fmaxf(m, __shfl_xor(m, 2));
            m = fmaxf(m, __shfl_xor(m, 4));
            m = fmaxf(m, __shfl_xor(m, 8));
            float sc = m * (1.f / 255.f);
            float inv = (m > 0.f) ? 255.f / m : 0.f;
            int grow = row0 + quad * 4 + r;
            if (l16 == r && grow < n) scales[grow * 2 + br] = sc;
#pragma unroll
            for (int nt = 0; nt < 8; ++nt) {
                uint32 u = (uint32)__float2int_rn(acc2_[nt][r] * inv);
                hs8[(quad * 4 + r) * 144 + nt * 16 + l16] = (unsigned char)u;
            }
        }
        int grow = row0 + l16;
        if (grow < n) {
            *(uint4*)(Y8 + (size_t)grow * 256 + br * 128 + quad * 32) =
                *(const uint4*)(hs8 + l16 * 144 + quad * 32);
            *(uint4*)(Y8 + (size_t)grow * 256 + br * 128 + quad * 32 + 16) =
                *(const uint4*)(hs8 + l16 * 144 + quad * 32 + 16);
        }
    }
    __syncthreads();
    if (tid < 128) {
        atomicAdd(&statsp[tid], ssum[tid]);
        atomicAdd(&statsp[128 + tid], ssq[tid]);
    }
}

// ---------------- dual pooling (coefs precomputed) ----------------
#define POOL_CHUNK 128
__global__ void pool_dual_kernel(const unsigned short* __restrict__ h,
                                 const float* __restrict__ coef2,
                                 const int* __restrict__ batch,
                                 float* __restrict__ poolA, float* __restrict__ poolB, int n) {
    int t = threadIdx.x;
    int br = t >> 7, cc = t & 127;
    float a = coef2[br * 256 + cc];
    float b = coef2[br * 256 + 128 + cc];
    float* pool = br ? poolB : poolA;

    int i0 = blockIdx.x * POOL_CHUNK;
    if (i0 >= n) return;
    int i1 = min(i0 + POOL_CHUNK, n);
    float acc = 0.f;
    int cur = batch[i0];
    for (int i = i0; i < i1; ++i) {
        int g = batch[i];
        if (g != cur) {
            atomicAdd(&pool[cur * 128 + cc], acc);
            acc = 0.f;
            cur = g;
        }
        acc += a * bf2f(h[(size_t)i * 256 + t]) + b;
    }
    atomicAdd(&pool[cur * 128 + cc], acc);
}

// ---------------- bilinear discriminator ----------------
__global__ void disc_kernel(const float* __restrict__ poolB, const float* __restrict__ cnt,
                            const float* __restrict__ W, const float* __restrict__ db,
                            float* __restrict__ out) {
    int g = blockIdx.x, e = threadIdx.x;
    __shared__ float rs[128], rh[128];
    float invc = 1.f / fmaxf(cnt[g], 1.f);
    int gs = (g == 32) ? 30 : (63 - g);
    float invcs = 1.f / fmaxf(cnt[gs], 1.f);
    const float* a = poolB + g * 128;
    float t = 0.f;
    for (int d = 0; d < 128; ++d) t += a[d] * W[d * 128 + e];
    t *= invc;
    rs[e] = t * poolB[g * 128 + e] * invc;
    rh[e] = t * poolB[gs * 128 + e] * invcs;
    __syncthreads();
    for (int s = 64; s > 0; s >>= 1) {
        if (e < s) { rs[e] += rs[e + s]; rh[e] += rh[e + s]; }
        __syncthreads();
    }
    if (e == 0) {
        out[GG * 10 + g] = rs[0] + db[0];
        out[GG * 10 + GG + g] = rh[0] + db[0];
    }
}

// ---------------- classification head ----------------
__global__ void head_kernel(const float* __restrict__ poolA, const float* __restrict__ poolB,
                            const float* __restrict__ cnt,
                            const float* __restrict__ w1, const float* __restrict__ b1,
                            const float* __restrict__ w2, const float* __restrict__ b2,
                            float* __restrict__ out) {
    int g = blockIdx.x, j = threadIdx.x;
    __shared__ float s1[128];
    __shared__ float s2[10];
    __shared__ float lse;
    float invc = 1.f / fmaxf(cnt[g], 1.f);
    const float* ma = poolA + g * 128;
    const float* px = poolB + g * 128;
    float acc = b1[j];
    for (int k = 0; k < 128; ++k) acc += ma[k] * invc * w1[k * 128 + j];
    for (int k = 0; k < 128; ++k) acc += px[k] * invc * w1[(128 + k) * 128 + j];
    s1[j] = fmaxf(acc, 0.f);
    __syncthreads();
    if (j < 10) {
        float a = b2[j];
        for (int k = 0; k < 128; ++k) a += s1[k] * w2[k * 10 + j];
        s2[j] = a;
    }
    __syncthreads();
    if (j == 0) {
        float m = s2[0];
        for (int o = 1; o < 10; ++o) m = fmaxf(m, s2[o]);
        float se = 0.f;
        for (int o = 0; o < 10; ++o) se += expf(s2[o] - m);
        lse = m + logf(se);
    }
    __syncthreads();
    if (j < 10) out[g * 10 + j] = s2[j] - lse;
}

extern "C" void kernel_launch(void* const* d_in, const int* in_sizes, int n_in,
                              void* d_out, int out_size, void* d_ws, size_t ws_size,
                              hipStream_t stream) {
    const float* x     = (const float*)d_in[0];
    const int*   ei    = (const int*)d_in[1];
    const int*   batch = (const int*)d_in[2];
    const float* W1a = (const float*)d_in[3];
    const float* b1a = (const float*)d_in[4];
    const float* W2a = (const float*)d_in[5];
    const float* b2a = (const float*)d_in[6];
    const float* ga  = (const float*)d_in[7];
    const float* bta = (const float*)d_in[8];
    const float* W1b = (const float*)d_in[9];
    const float* b1b = (const float*)d_in[10];
    const float* W2b = (const float*)d_in[11];
    const float* b2b = (const float*)d_in[12];
    const float* gb  = (const float*)d_in[13];
    const float* btb = (const float*)d_in[14];
    const float* lin1_w = (const float*)d_in[15];
    const float* lin1_b = (const float*)d_in[16];
    const float* lin2_w = (const float*)d_in[17];
    const float* lin2_b = (const float*)d_in[18];
    const float* disc_w = (const float*)d_in[19];
    const float* disc_b = (const float*)d_in[20];
    float* out = (float*)d_out;

    const int* src = ei;
    const int* dst = ei + EE;

    size_t o = 0;
    auto take = [&](size_t b) { size_t p = o; o = (o + b + 255) & ~(size_t)255; return p; };
    uint8_t* w = (uint8_t*)d_ws;
    size_t o_x8   = take((size_t)NN * 128);
    size_t o_sc0  = take((size_t)NN * 4);
    size_t o_g0   = take((size_t)NN * 128 * 2);
    size_t o_bufP = take((size_t)NN * 256 * 2);
    size_t o_gbuf = take((size_t)NN * 256 * 2);
    size_t o_y8a  = take((size_t)NN * 256);
    size_t o_y8b  = take((size_t)NN * 256);
    size_t o_scA  = take((size_t)NN * 2 * 4);
    size_t o_scB  = take((size_t)NN * 2 * 4);
    size_t o_wf   = take((size_t)12 * MAT_STRIDE * 2);
    size_t o_col  = take((size_t)NBUCK * BCAP * 4);
    size_t o_part = take((size_t)NBUCK * BCAP * 4);
    size_t o_rowpair = take((size_t)NN * 8);
    size_t o_coef = take((size_t)3 * 2 * 256 * 4);
    size_t zero_begin = o;
    size_t o_bcnt   = take((size_t)NBUCK * 4);
    size_t o_stats  = take((size_t)6 * NREP * 256 * 4);
    size_t o_cnt    = take(GG * 4);
    size_t o_poolA  = take((size_t)GG * 128 * 4);
    size_t o_poolB  = take((size_t)GG * 128 * 4);
    size_t zero_end = o;

    unsigned short* x8 = (unsigned short*)(w + o_x8);
    float* sc0 = (float*)(w + o_sc0);
    uint32* g0 = (uint32*)(w + o_g0);
    unsigned short* bufP = (unsigned short*)(w + o_bufP);
    unsigned short* gbuf = (unsigned short*)(w + o_gbuf);
    unsigned char* y8a = (unsigned char*)(w + o_y8a);
    unsigned char* y8b = (unsigned char*)(w + o_y8b);
    float* scA = (float*)(w + o_scA);
    float* scB = (float*)(w + o_scB);
    unsigned short* wf = (unsigned short*)(w + o_wf);
    int* col = (int*)(w + o_col);
    uint32* part = (uint32*)(w + o_part);
    int2* rowpair = (int2*)(w + o_rowpair);
    float* coef = (float*)(w + o_coef);
    int* bcnt = (int*)(w + o_bcnt);
    float* statsRep = (float*)(w + o_stats);
    float* cnt = (float*)(w + o_cnt);
    float* poolA = (float*)(w + o_poolA);
    float* poolB = (float*)(w + o_poolB);

    hipMemsetAsync(w + zero_begin, 0, zero_end - zero_begin, stream);

    x_to_i8_kernel<<<(NN * 64 + 255) / 256, 256, 0, stream>>>(x, x8, sc0);
    convert_w_kernel<<<(24576 + 255) / 256, 256, 0, stream>>>(W1a, W2a, W1b, W2b, wf);

    partition_kernel<<<(EE + PART_CHUNK - 1) / PART_CHUNK, 256, 0, stream>>>(src, dst, bcnt, part);
    build_col_kernel<<<NBUCK, 256, 0, stream>>>(part, bcnt, col, rowpair);
    counts_kernel<<<(NN + 255) / 256, 256, 0, stream>>>(batch, cnt, NN);

    int gatherBlocks = (NN + 3) / 4;
    dim3 mlpGrid((NN + 127) / 128, 2);
    size_t ldsBytes = (size_t)LDS_W1 * 2 + (size_t)LDS_HS * 2 + 256 * 4;  // 68608

    gather0_kernel<<<gatherBlocks, 256, 0, stream>>>((const uint32*)x8, sc0, rowpair, col, (uint2*)g0);

    // layer 0: g0 -> y8a
    mlp_dual_kernel<<<mlpGrid, 512, ldsBytes, stream>>>(
        (const unsigned short*)g0, 128, 0, wf, b1a, b1b, b2a, b2b, 0, 1,
        nullptr, y8a, scA, statsRep, NN);
    bn_coefs_kernel<<<1, 256, 0, stream>>>(statsRep, ga, bta, gb, btb, 0, coef + 0 * 512);

    // layer 1: gather(y8a) -> gbuf; mlp -> y8b
    gather_dual_kernel<<<gatherBlocks, 256, 0, stream>>>(
        (const uint32*)y8a, scA, rowpair, col, coef + 0 * 512, (uint2*)gbuf);
    mlp_dual_kernel<<<mlpGrid, 512, ldsBytes, stream>>>(
        gbuf, 256, 128, wf, b1a, b1b, b2a, b2b, 1, 1,
        nullptr, y8b, scB, statsRep, NN);
    bn_coefs_kernel<<<1, 256, 0, stream>>>(statsRep, ga, bta, gb, btb, 1, coef + 1 * 512);

    // layer 2: gather(y8b) -> gbuf; mlp -> bufP (bf16)
    gather_dual_kernel<<<gatherBlocks, 256, 0, stream>>>(
        (const uint32*)y8b, scB, rowpair, col, coef + 1 * 512, (uint2*)gbuf);
    mlp_dual_kernel<<<mlpGrid, 512, ldsBytes, stream>>>(
        gbuf, 256, 128, wf, b1a, b1b, b2a, b2b, 2, 0,
        bufP, nullptr, nullptr, statsRep, NN);
    bn_coefs_kernel<<<1, 256, 0, stream>>>(statsRep, ga, bta, gb, btb, 2, coef + 2 * 512);

    pool_dual_kernel<<<(NN + POOL_CHUNK - 1) / POOL_CHUNK, 256, 0, stream>>>(
        bufP, coef + 2 * 512, batch, poolA, poolB, NN);
    disc_kernel<<<GG, 128, 0, stream>>>(poolB, cnt, disc_w, disc_b, out);
    head_kernel<<<GG, 128, 0, stream>>>(poolA, poolB, cnt, lin1_w, lin1_b, lin2_w, lin2_b, out);
}